// Round 1
// baseline (7146.600 us; speedup 1.0000x reference)
//
#include <hip/hip_runtime.h>

// Multi-layer tanh RNN, layer-pipelined persistent kernel.
// Block (layer, chunk) keeps layer weights transposed in LDS for the whole
// run; activations flow layer->layer+1 through a D=2 ring in d_ws guarded by
// agent-scope acquire/release progress/consumed counters.
// Grid = 10*16 = 160 blocks, 1 block/CU (137KB LDS) -> all co-resident.

#define HH   100   // hidden
#define HP   128   // padded j dimension
#define NL   10    // layers
#define BBS  512   // batch
#define TTS  512   // time
#define NB   16    // batch chunks
#define BC   32    // batch per chunk
#define RD   2     // ring depth (timesteps)
#define NT   256   // threads per block

// d_ws layout:
//   bytes [0,      9216)  prog[iface][chunk] padded to 16 ints (64B)
//   bytes [32768, 41984)  cons[iface][chunk] padded to 16 ints
//   bytes [65536, ...  )  ring: (iface*NB+chunk) * RD slots of BC*HH floats
//   total needed: 65536 + 9*16*2*3200*4 = ~3.75 MB

__global__ void init_ws_kernel(int* wsi) {
  int i = blockIdx.x * blockDim.x + threadIdx.x;
  if (i < 16384) wsi[i] = 0;   // zero both flag regions (64KB)
}

__device__ __forceinline__ int flag_idx(int iface, int chunk) {
  return (iface * NB + chunk) * 16;
}

__global__ __launch_bounds__(NT, 1) void rnn_pipe(
    const float* __restrict__ x,     // [B,T,1]
    const float* __restrict__ h0,    // [L,B,H]
    const float* __restrict__ Wih0,  // [H,1]
    const float* __restrict__ Wih,   // [L-1,H,H]
    const float* __restrict__ Whh,   // [L,H,H]
    const float* __restrict__ bih,   // [L,H]
    const float* __restrict__ bhh,   // [L,H]
    const float* __restrict__ Wout,  // [1,H]
    const float* __restrict__ bout,  // [1]
    float* __restrict__ out,         // [B*T] outs ++ [L*B*H] h_final
    float* __restrict__ ring,
    int*   __restrict__ wsi)
{
  const int layer = blockIdx.x / NB;
  const int chunk = blockIdx.x % NB;
  const int tid   = threadIdx.x;

  // LDS: 51200*2 + 512*3 + 16384*2 + 128 + 512 = 137344 B  (<160KiB, 1 blk/CU)
  __shared__ float Wt_i[HH][HP];   // transposed W_ih[layer-1]: Wt_i[k][j]
  __shared__ float Wt_h[HH][HP];   // transposed W_hh[layer]
  __shared__ float bias[HP];       // b_ih + b_hh, zero-padded
  __shared__ float wi0s[HP];       // W_ih0 (layer 0 only)
  __shared__ float wouts[HP];      // W_out (layer 9 only)
  __shared__ float hbuf[BC][HP];   // recurrent state, cols >=100 stay 0
  __shared__ float ibuf[BC][HP];   // staged input from previous layer
  __shared__ float xin[BC];        // layer-0 scalar inputs
  __shared__ float red[4][BC];     // layer-9 output reduction

  // ---- one-time LDS init ----
  for (int i = tid; i < HH * HP; i += NT) { (&Wt_i[0][0])[i] = 0.f; (&Wt_h[0][0])[i] = 0.f; }
  for (int i = tid; i < BC * HP; i += NT) { (&hbuf[0][0])[i] = 0.f; (&ibuf[0][0])[i] = 0.f; }
  for (int i = tid; i < HP; i += NT) {
    bias[i]  = (i < HH) ? (bih[layer * HH + i] + bhh[layer * HH + i]) : 0.f;
    wi0s[i]  = (i < HH) ? Wih0[i] : 0.f;
    wouts[i] = (i < HH) ? Wout[i] : 0.f;
  }
  __syncthreads();
  if (layer > 0) {
    const float* Wi = Wih + (size_t)(layer - 1) * HH * HH;
    for (int idx = tid; idx < HH * HH; idx += NT)
      Wt_i[idx % HH][idx / HH] = Wi[idx];          // [j][k] -> [k][j]
  }
  {
    const float* Wh = Whh + (size_t)layer * HH * HH;
    for (int idx = tid; idx < HH * HH; idx += NT)
      Wt_h[idx % HH][idx / HH] = Wh[idx];
  }
  for (int idx = tid; idx < BC * HH; idx += NT)
    hbuf[idx / HH][idx % HH] =
        h0[((size_t)layer * BBS + chunk * BC + idx / HH) * HH + idx % HH];
  __syncthreads();

  // ---- flags / ring pointers ----
  int* prog_in  = (layer > 0)      ? wsi + flag_idx(layer - 1, chunk)        : nullptr;
  int* cons_in  = (layer > 0)      ? wsi + 8192 + flag_idx(layer - 1, chunk) : nullptr;
  int* prog_out = (layer < NL - 1) ? wsi + flag_idx(layer, chunk)            : nullptr;
  int* cons_out = (layer < NL - 1) ? wsi + 8192 + flag_idx(layer, chunk)     : nullptr;
  const size_t slot_sz = (size_t)BC * HH;  // 3200 floats
  float* ring_in  = (layer > 0)      ? ring + (size_t)((layer - 1) * NB + chunk) * RD * slot_sz : nullptr;
  float* ring_out = (layer < NL - 1) ? ring + (size_t)(layer * NB + chunk) * RD * slot_sz       : nullptr;

  const int jt = tid & 31, bt = tid >> 5;
  const int j0 = jt * 4,   b0 = bt * 4;

  float w0r[4];
  #pragma unroll
  for (int jj = 0; jj < 4; ++jj) w0r[jj] = wi0s[j0 + jj];
  const float boutv = bout[0];

  for (int t = 0; t < TTS; ++t) {
    // ---- wait for producer data / consumer backpressure (thread 0 spins) ----
    if (tid == 0) {
      if (layer > 0) {
        while (__hip_atomic_load(prog_in, __ATOMIC_RELAXED, __HIP_MEMORY_SCOPE_AGENT) < t + 1)
          __builtin_amdgcn_s_sleep(8);
        (void)__hip_atomic_load(prog_in, __ATOMIC_ACQUIRE, __HIP_MEMORY_SCOPE_AGENT);
      }
      if (layer < NL - 1 && t >= RD) {
        while (__hip_atomic_load(cons_out, __ATOMIC_RELAXED, __HIP_MEMORY_SCOPE_AGENT) < t - RD + 1)
          __builtin_amdgcn_s_sleep(8);
      }
    }
    __syncthreads();

    // ---- stage input ----
    if (layer == 0) {
      if (tid < BC) xin[tid] = x[(size_t)(chunk * BC + tid) * TTS + t];
    } else {
      const float* src = ring_in + (size_t)(t % RD) * slot_sz;
      for (int i = tid * 4; i < BC * HH; i += NT * 4) {
        float4 v = *(const float4*)(src + i);
        *(float4*)&ibuf[i / HH][i % HH] = v;   // i%4==0 and HH%4==0 -> k%4==0
      }
    }
    __syncthreads();
    if (layer > 0 && tid == 0)
      __hip_atomic_store(cons_in, t + 1, __ATOMIC_RELEASE, __HIP_MEMORY_SCOPE_AGENT);

    // ---- compute 4b x 4j tile: acc = inp@Wi^T + h@Whh^T ----
    float acc[4][4];
    #pragma unroll
    for (int bb = 0; bb < 4; ++bb)
      #pragma unroll
      for (int jj = 0; jj < 4; ++jj) acc[bb][jj] = 0.f;

    if (layer == 0) {
      for (int k = 0; k < HH; k += 4) {
        float4 wv[4];
        #pragma unroll
        for (int i = 0; i < 4; ++i) wv[i] = *(const float4*)&Wt_h[k + i][j0];
        #pragma unroll
        for (int bb = 0; bb < 4; ++bb) {
          float4 hv = *(const float4*)&hbuf[b0 + bb][k];
          const float* hp = (const float*)&hv;
          #pragma unroll
          for (int i = 0; i < 4; ++i) {
            const float* wp = (const float*)&wv[i];
            #pragma unroll
            for (int jj = 0; jj < 4; ++jj) acc[bb][jj] += hp[i] * wp[jj];
          }
        }
      }
    } else {
      for (int k = 0; k < HH; k += 4) {
        float4 wv[4], uv[4];
        #pragma unroll
        for (int i = 0; i < 4; ++i) {
          wv[i] = *(const float4*)&Wt_h[k + i][j0];
          uv[i] = *(const float4*)&Wt_i[k + i][j0];
        }
        #pragma unroll
        for (int bb = 0; bb < 4; ++bb) {
          float4 hv = *(const float4*)&hbuf[b0 + bb][k];
          float4 iv = *(const float4*)&ibuf[b0 + bb][k];
          const float* hp = (const float*)&hv;
          const float* ip = (const float*)&iv;
          #pragma unroll
          for (int i = 0; i < 4; ++i) {
            const float* wp = (const float*)&wv[i];
            const float* up = (const float*)&uv[i];
            #pragma unroll
            for (int jj = 0; jj < 4; ++jj)
              acc[bb][jj] += hp[i] * wp[jj] + ip[i] * up[jj];
          }
        }
      }
    }

    // ---- activation ----
    float hnew[4][4];
    if (layer == 0) {
      #pragma unroll
      for (int bb = 0; bb < 4; ++bb) {
        float xb = xin[b0 + bb];
        #pragma unroll
        for (int jj = 0; jj < 4; ++jj)
          hnew[bb][jj] = tanhf(acc[bb][jj] + xb * w0r[jj] + bias[j0 + jj]);
      }
    } else {
      #pragma unroll
      for (int bb = 0; bb < 4; ++bb)
        #pragma unroll
        for (int jj = 0; jj < 4; ++jj)
          hnew[bb][jj] = tanhf(acc[bb][jj] + bias[j0 + jj]);
    }

    __syncthreads();  // all tiles done reading old hbuf/ibuf
    #pragma unroll
    for (int bb = 0; bb < 4; ++bb)
      *(float4*)&hbuf[b0 + bb][j0] =
          make_float4(hnew[bb][0], hnew[bb][1], hnew[bb][2], hnew[bb][3]);

    if (layer < NL - 1 && j0 < HH) {          // publish activations to ring
      float* dst = ring_out + (size_t)(t % RD) * slot_sz;
      #pragma unroll
      for (int bb = 0; bb < 4; ++bb)
        *(float4*)(dst + (size_t)(b0 + bb) * HH + j0) =
            make_float4(hnew[bb][0], hnew[bb][1], hnew[bb][2], hnew[bb][3]);
    }
    if (t == TTS - 1 && j0 < HH) {            // final hidden state
      #pragma unroll
      for (int bb = 0; bb < 4; ++bb)
        *(float4*)(out + (size_t)BBS * TTS +
                   ((size_t)layer * BBS + chunk * BC + b0 + bb) * HH + j0) =
            make_float4(hnew[bb][0], hnew[bb][1], hnew[bb][2], hnew[bb][3]);
    }
    __syncthreads();  // ring + hbuf writes complete

    if (layer < NL - 1 && tid == 0)
      __hip_atomic_store(prog_out, t + 1, __ATOMIC_RELEASE, __HIP_MEMORY_SCOPE_AGENT);

    if (layer == NL - 1) {                    // top layer: outs[b][t] = h . Wout + b
      if (tid < 128) {
        int b = tid & 31, seg = tid >> 5;
        float s = 0.f;
        for (int j = seg * 25; j < seg * 25 + 25; ++j) s += hbuf[b][j] * wouts[j];
        red[seg][b] = s;
      }
      __syncthreads();
      if (tid < BC)
        out[(size_t)(chunk * BC + tid) * TTS + t] =
            red[0][tid] + red[1][tid] + red[2][tid] + red[3][tid] + boutv;
    }
  }
}

extern "C" void kernel_launch(void* const* d_in, const int* in_sizes, int n_in,
                              void* d_out, int out_size, void* d_ws, size_t ws_size,
                              hipStream_t stream) {
  const float* x    = (const float*)d_in[0];
  const float* h0   = (const float*)d_in[1];
  const float* Wih0 = (const float*)d_in[2];
  const float* Wih  = (const float*)d_in[3];
  const float* Whh  = (const float*)d_in[4];
  const float* bih  = (const float*)d_in[5];
  const float* bhh  = (const float*)d_in[6];
  const float* Wout = (const float*)d_in[7];
  const float* bout = (const float*)d_in[8];
  float* out = (float*)d_out;

  int*   wsi  = (int*)d_ws;
  float* ring = (float*)((char*)d_ws + 65536);

  hipLaunchKernelGGL(init_ws_kernel, dim3(64), dim3(256), 0, stream, wsi);
  hipLaunchKernelGGL(rnn_pipe, dim3(NL * NB), dim3(NT), 0, stream,
                     x, h0, Wih0, Wih, Whh, bih, bhh, Wout, bout, out, ring, wsi);
}

// Round 2
// 6105.074 us; speedup vs baseline: 1.1706x; 1.1706x over previous
//
#include <hip/hip_runtime.h>

// Multi-layer tanh RNN, layer-pipelined persistent kernel, K-step batched sync.
// Block (layer, chunk) keeps layer weights transposed in LDS for the whole run;
// activations flow layer->layer+1 through a ring in d_ws. Flags are published
// once per K timesteps (K = RD/2, ring double-buffers batches) to amortize the
// agent-scope release (L2 writeback + flag RTT) that R1 counters showed costs
// ~11us/step. RD chosen at runtime from ws_size; RD=2/K=1 == proven R1 config.
// Grid = 10*16 = 160 blocks, 1 block/CU (137KB LDS) -> all co-resident.
// blockIdx = layer*16 + chunk -> blockIdx%8 = chunk%8: all layers of a chunk
// land on one XCD (round-robin heuristic; correctness does not depend on it).

#define HH   100   // hidden
#define HP   128   // padded j dimension
#define NL   10    // layers
#define BBS  512   // batch
#define TTS  512   // time
#define NB   16    // batch chunks
#define BC   32    // batch per chunk
#define NT   256   // threads per block

// d_ws layout:
//   bytes [0,      32768)  prog[iface][chunk] padded to 16 ints
//   bytes [32768,  65536)  cons[iface][chunk] padded to 16 ints
//   bytes [65536,  ...  )  ring: (iface*NB+chunk) * RD slots of BC*HH floats

__global__ void init_ws_kernel(int* wsi) {
  int i = blockIdx.x * blockDim.x + threadIdx.x;
  if (i < 16384) wsi[i] = 0;   // zero both flag regions (64KB)
}

__device__ __forceinline__ int flag_idx(int iface, int chunk) {
  return (iface * NB + chunk) * 16;
}

__global__ __launch_bounds__(NT, 1) void rnn_pipe(
    const float* __restrict__ x,     // [B,T,1]
    const float* __restrict__ h0,    // [L,B,H]
    const float* __restrict__ Wih0,  // [H,1]
    const float* __restrict__ Wih,   // [L-1,H,H]
    const float* __restrict__ Whh,   // [L,H,H]
    const float* __restrict__ bih,   // [L,H]
    const float* __restrict__ bhh,   // [L,H]
    const float* __restrict__ Wout,  // [1,H]
    const float* __restrict__ bout,  // [1]
    float* __restrict__ out,         // [B*T] outs ++ [L*B*H] h_final
    float* __restrict__ ring,
    int*   __restrict__ wsi,
    int Kv, int RDv)                 // batch steps per flag, ring depth (pow2)
{
  const int layer = blockIdx.x / NB;
  const int chunk = blockIdx.x % NB;
  const int tid   = threadIdx.x;
  const int Km = Kv - 1, RDm = RDv - 1;

  // LDS: 51200*2 + 16384*2 + 128*3 + 128 + 512 = 137344 B (<160KiB, 1 blk/CU)
  __shared__ float Wt_i[HH][HP];   // transposed W_ih[layer-1]: Wt_i[k][j]
  __shared__ float Wt_h[HH][HP];   // transposed W_hh[layer]
  __shared__ float bias[HP];       // b_ih + b_hh, zero-padded
  __shared__ float wi0s[HP];       // W_ih0 (layer 0 only)
  __shared__ float wouts[HP];      // W_out (layer 9 only)
  __shared__ float hbuf[BC][HP];   // recurrent state, cols >=100 stay 0
  __shared__ float ibuf[BC][HP];   // staged input from previous layer
  __shared__ float xin[BC];        // layer-0 scalar inputs
  __shared__ float red[4][BC];     // layer-9 output reduction

  // ---- one-time LDS init ----
  for (int i = tid; i < HH * HP; i += NT) { (&Wt_i[0][0])[i] = 0.f; (&Wt_h[0][0])[i] = 0.f; }
  for (int i = tid; i < BC * HP; i += NT) { (&hbuf[0][0])[i] = 0.f; (&ibuf[0][0])[i] = 0.f; }
  for (int i = tid; i < HP; i += NT) {
    bias[i]  = (i < HH) ? (bih[layer * HH + i] + bhh[layer * HH + i]) : 0.f;
    wi0s[i]  = (i < HH) ? Wih0[i] : 0.f;
    wouts[i] = (i < HH) ? Wout[i] : 0.f;
  }
  __syncthreads();
  if (layer > 0) {
    const float* Wi = Wih + (size_t)(layer - 1) * HH * HH;
    for (int idx = tid; idx < HH * HH; idx += NT)
      Wt_i[idx % HH][idx / HH] = Wi[idx];          // [j][k] -> [k][j]
  }
  {
    const float* Wh = Whh + (size_t)layer * HH * HH;
    for (int idx = tid; idx < HH * HH; idx += NT)
      Wt_h[idx % HH][idx / HH] = Wh[idx];
  }
  for (int idx = tid; idx < BC * HH; idx += NT)
    hbuf[idx / HH][idx % HH] =
        h0[((size_t)layer * BBS + chunk * BC + idx / HH) * HH + idx % HH];
  __syncthreads();

  // ---- flags / ring pointers ----
  int* prog_in  = (layer > 0)      ? wsi + flag_idx(layer - 1, chunk)        : nullptr;
  int* cons_in  = (layer > 0)      ? wsi + 8192 + flag_idx(layer - 1, chunk) : nullptr;
  int* prog_out = (layer < NL - 1) ? wsi + flag_idx(layer, chunk)            : nullptr;
  int* cons_out = (layer < NL - 1) ? wsi + 8192 + flag_idx(layer, chunk)     : nullptr;
  const size_t slot_sz = (size_t)BC * HH;  // 3200 floats
  float* ring_in  = (layer > 0)      ? ring + (size_t)((layer - 1) * NB + chunk) * RDv * slot_sz : nullptr;
  float* ring_out = (layer < NL - 1) ? ring + (size_t)(layer * NB + chunk) * RDv * slot_sz       : nullptr;

  const int jt = tid & 31, bt = tid >> 5;
  const int j0 = jt * 4,   b0 = bt * 4;

  float w0r[4];
  #pragma unroll
  for (int jj = 0; jj < 4; ++jj) w0r[jj] = wi0s[j0 + jj];
  const float boutv = bout[0];

  for (int t = 0; t < TTS; ++t) {
    // ---- batch-start: wait for producer batch / consumer backpressure ----
    if ((t & Km) == 0) {
      if (tid == 0) {
        if (layer > 0) {
          while (__hip_atomic_load(prog_in, __ATOMIC_RELAXED, __HIP_MEMORY_SCOPE_AGENT) < t + Kv)
            __builtin_amdgcn_s_sleep(2);
          (void)__hip_atomic_load(prog_in, __ATOMIC_ACQUIRE, __HIP_MEMORY_SCOPE_AGENT);
        }
        if (layer < NL - 1 && t + Kv > RDv) {
          while (__hip_atomic_load(cons_out, __ATOMIC_RELAXED, __HIP_MEMORY_SCOPE_AGENT) < t + Kv - RDv)
            __builtin_amdgcn_s_sleep(2);
        }
      }
      __syncthreads();
    }

    // ---- stage input for step t ----
    if (layer == 0) {
      if (tid < BC) xin[tid] = x[(size_t)(chunk * BC + tid) * TTS + t];
    } else {
      const float* src = ring_in + (size_t)(t & RDm) * slot_sz;
      for (int i = tid * 4; i < BC * HH; i += NT * 4) {
        float4 v = *(const float4*)(src + i);
        *(float4*)&ibuf[i / HH][i % HH] = v;   // i%4==0 and HH%4==0 -> k%4==0
      }
    }
    __syncthreads();
    // consumer publishes consumption once per batch (after last stage of batch)
    if (layer > 0 && (t & Km) == Km && tid == 0)
      __hip_atomic_store(cons_in, t + 1, __ATOMIC_RELEASE, __HIP_MEMORY_SCOPE_AGENT);

    // ---- compute 4b x 4j tile: acc = inp@Wi^T + h@Whh^T ----
    float acc[4][4];
    #pragma unroll
    for (int bb = 0; bb < 4; ++bb)
      #pragma unroll
      for (int jj = 0; jj < 4; ++jj) acc[bb][jj] = 0.f;

    if (layer == 0) {
      for (int k = 0; k < HH; k += 4) {
        float4 wv[4];
        #pragma unroll
        for (int i = 0; i < 4; ++i) wv[i] = *(const float4*)&Wt_h[k + i][j0];
        #pragma unroll
        for (int bb = 0; bb < 4; ++bb) {
          float4 hv = *(const float4*)&hbuf[b0 + bb][k];
          const float* hp = (const float*)&hv;
          #pragma unroll
          for (int i = 0; i < 4; ++i) {
            const float* wp = (const float*)&wv[i];
            #pragma unroll
            for (int jj = 0; jj < 4; ++jj) acc[bb][jj] += hp[i] * wp[jj];
          }
        }
      }
    } else {
      for (int k = 0; k < HH; k += 4) {
        float4 wv[4], uv[4];
        #pragma unroll
        for (int i = 0; i < 4; ++i) {
          wv[i] = *(const float4*)&Wt_h[k + i][j0];
          uv[i] = *(const float4*)&Wt_i[k + i][j0];
        }
        #pragma unroll
        for (int bb = 0; bb < 4; ++bb) {
          float4 hv = *(const float4*)&hbuf[b0 + bb][k];
          float4 iv = *(const float4*)&ibuf[b0 + bb][k];
          const float* hp = (const float*)&hv;
          const float* ip = (const float*)&iv;
          #pragma unroll
          for (int i = 0; i < 4; ++i) {
            const float* wp = (const float*)&wv[i];
            const float* up = (const float*)&uv[i];
            #pragma unroll
            for (int jj = 0; jj < 4; ++jj)
              acc[bb][jj] += hp[i] * wp[jj] + ip[i] * up[jj];
          }
        }
      }
    }

    // ---- activation ----
    float hnew[4][4];
    if (layer == 0) {
      #pragma unroll
      for (int bb = 0; bb < 4; ++bb) {
        float xb = xin[b0 + bb];
        #pragma unroll
        for (int jj = 0; jj < 4; ++jj)
          hnew[bb][jj] = tanhf(acc[bb][jj] + xb * w0r[jj] + bias[j0 + jj]);
      }
    } else {
      #pragma unroll
      for (int bb = 0; bb < 4; ++bb)
        #pragma unroll
        for (int jj = 0; jj < 4; ++jj)
          hnew[bb][jj] = tanhf(acc[bb][jj] + bias[j0 + jj]);
    }

    __syncthreads();  // all tiles done reading old hbuf/ibuf
    #pragma unroll
    for (int bb = 0; bb < 4; ++bb)
      *(float4*)&hbuf[b0 + bb][j0] =
          make_float4(hnew[bb][0], hnew[bb][1], hnew[bb][2], hnew[bb][3]);

    if (layer < NL - 1 && j0 < HH) {          // publish activations to ring
      float* dst = ring_out + (size_t)(t & RDm) * slot_sz;
      #pragma unroll
      for (int bb = 0; bb < 4; ++bb)
        *(float4*)(dst + (size_t)(b0 + bb) * HH + j0) =
            make_float4(hnew[bb][0], hnew[bb][1], hnew[bb][2], hnew[bb][3]);
    }
    if (t == TTS - 1 && j0 < HH) {            // final hidden state
      #pragma unroll
      for (int bb = 0; bb < 4; ++bb)
        *(float4*)(out + (size_t)BBS * TTS +
                   ((size_t)layer * BBS + chunk * BC + b0 + bb) * HH + j0) =
            make_float4(hnew[bb][0], hnew[bb][1], hnew[bb][2], hnew[bb][3]);
    }
    __syncthreads();  // ring + hbuf writes complete (vmcnt drained per-wave)

    // producer publishes progress once per batch
    if (layer < NL - 1 && (t & Km) == Km && tid == 0)
      __hip_atomic_store(prog_out, t + 1, __ATOMIC_RELEASE, __HIP_MEMORY_SCOPE_AGENT);

    if (layer == NL - 1) {                    // top layer: outs[b][t] = h . Wout + b
      if (tid < 128) {
        int b = tid & 31, seg = tid >> 5;
        float s = 0.f;
        for (int j = seg * 25; j < seg * 25 + 25; ++j) s += hbuf[b][j] * wouts[j];
        red[seg][b] = s;
      }
      __syncthreads();
      if (tid < BC)
        out[(size_t)(chunk * BC + tid) * TTS + t] =
            red[0][tid] + red[1][tid] + red[2][tid] + red[3][tid] + boutv;
    }
  }
}

extern "C" void kernel_launch(void* const* d_in, const int* in_sizes, int n_in,
                              void* d_out, int out_size, void* d_ws, size_t ws_size,
                              hipStream_t stream) {
  const float* x    = (const float*)d_in[0];
  const float* h0   = (const float*)d_in[1];
  const float* Wih0 = (const float*)d_in[2];
  const float* Wih  = (const float*)d_in[3];
  const float* Whh  = (const float*)d_in[4];
  const float* bih  = (const float*)d_in[5];
  const float* bhh  = (const float*)d_in[6];
  const float* Wout = (const float*)d_in[7];
  const float* bout = (const float*)d_in[8];
  float* out = (float*)d_out;

  int*   wsi  = (int*)d_ws;
  float* ring = (float*)((char*)d_ws + 65536);

  // Pick deepest ring that fits ws: ring bytes = 144 * RD * 12800
  const size_t slot_bytes = (size_t)BC * HH * 4;   // 12800
  int RDv = 16;
  while (RDv > 2 && 65536 + (size_t)(NL - 1) * NB * RDv * slot_bytes > ws_size)
    RDv >>= 1;
  int Kv = RDv / 2;   // double-buffered batches; RD=2/K=1 == R1 proven config

  hipLaunchKernelGGL(init_ws_kernel, dim3(64), dim3(256), 0, stream, wsi);
  hipLaunchKernelGGL(rnn_pipe, dim3(NL * NB), dim3(NT), 0, stream,
                     x, h0, Wih0, Wih, Whh, bih, bhh, Wout, bout, out, ring, wsi,
                     Kv, RDv);
}

// Round 3
// 4184.002 us; speedup vs baseline: 1.7081x; 1.4591x over previous
//
#include <hip/hip_runtime.h>

// Multi-layer tanh RNN, layer-pipelined persistent kernel.
// R3: LDS-bandwidth attack. R2 counters closed on LDS raw-byte bound
// (1.64 MB/step/CU at ~85 B/cyc == the 8us/step dark matter). Changes:
//  - split-matrix thread halves: tid<128 computes h@Whh^T (8b x 4j tile),
//    tid>=128 computes inp@Wih^T; partials merged via pbuf LDS.
//    B/FMA 2.0 -> 1.5, FMA wall unchanged (4 waves on 4 SIMDs).
//  - register prefetch of next-step ring/x staging (global latency hidden
//    under compute), ring/out stores deferred one step (store-ack hidden).
//  - 2 barriers/step (shfl reduction for layer-9 output, no red[] buffer).
//  - fast tanh: 1 - 2*rcp(exp(2x)+1) (v_exp_f32 + v_rcp_f32), err ~1e-6.
// Flag protocol identical to R2 (proven): per-K-step batched acquire/release.
// Grid = 10*16 = 160 blocks, 1 block/CU (153KB LDS) -> all co-resident.

#define HH   100   // hidden
#define HP   128   // padded j dimension
#define NL   10    // layers
#define BBS  512   // batch
#define TTS  512   // time
#define NB   16    // batch chunks
#define BC   32    // batch per chunk
#define NT   256   // threads per block

__global__ void init_ws_kernel(int* wsi) {
  int i = blockIdx.x * blockDim.x + threadIdx.x;
  if (i < 16384) wsi[i] = 0;   // zero both flag regions (64KB)
}

__device__ __forceinline__ int flag_idx(int iface, int chunk) {
  return (iface * NB + chunk) * 16;
}

__device__ __forceinline__ float fast_tanh(float v) {
  // tanh(v) = 1 - 2/(exp(2v)+1); exp overflow->inf->rcp->0->+1; underflow->-1.
  float e = __expf(2.0f * v);
  return 1.0f - 2.0f * __builtin_amdgcn_rcpf(e + 1.0f);
}

__global__ __launch_bounds__(NT, 1) void rnn_pipe(
    const float* __restrict__ x,     // [B,T,1]
    const float* __restrict__ h0,    // [L,B,H]
    const float* __restrict__ Wih0,  // [H,1]
    const float* __restrict__ Wih,   // [L-1,H,H]
    const float* __restrict__ Whh,   // [L,H,H]
    const float* __restrict__ bih,   // [L,H]
    const float* __restrict__ bhh,   // [L,H]
    const float* __restrict__ Wout,  // [1,H]
    const float* __restrict__ bout,  // [1]
    float* __restrict__ out,         // [B*T] outs ++ [L*B*H] h_final
    float* __restrict__ ring,
    int*   __restrict__ wsi,
    int Kv, int RDv)                 // steps per flag batch, ring depth (pow2)
{
  const int layer = blockIdx.x / NB;
  const int chunk = blockIdx.x % NB;
  const int tid   = threadIdx.x;
  const int Km = Kv - 1, RDm = RDv - 1;

  // LDS total: 2*51200 + 3*16384 + 3*512 + 128 = 153216 B (<160KiB, 1 blk/CU)
  __shared__ float Wt_h[HH][HP];   // transposed W_hh[layer]: [k][j]
  __shared__ float Wt_i[HH][HP];   // transposed W_ih[layer-1]
  __shared__ float hbuf[BC][HP];   // recurrent state, cols >=100 stay 0
  __shared__ float ibuf[BC][HP];   // staged input from previous layer
  __shared__ float pbuf[BC][HP];   // inp@Wih^T partials (half1 -> half0)
  __shared__ float bias[HP];       // b_ih + b_hh, zero-padded
  __shared__ float wi0s[HP];       // W_ih0 (layer 0 only)
  __shared__ float wouts[HP];      // W_out (layer 9 only)
  __shared__ float xin[BC];        // layer-0 scalar inputs

  // ---- one-time LDS init ----
  for (int i = tid; i < HH * HP; i += NT) { (&Wt_i[0][0])[i] = 0.f; (&Wt_h[0][0])[i] = 0.f; }
  for (int i = tid; i < BC * HP; i += NT) { (&hbuf[0][0])[i] = 0.f; (&ibuf[0][0])[i] = 0.f; }
  for (int i = tid; i < HP; i += NT) {
    bias[i]  = (i < HH) ? (bih[layer * HH + i] + bhh[layer * HH + i]) : 0.f;
    wi0s[i]  = (i < HH) ? Wih0[i] : 0.f;
    wouts[i] = (i < HH) ? Wout[i] : 0.f;
  }
  __syncthreads();
  if (layer > 0) {
    const float* Wi = Wih + (size_t)(layer - 1) * HH * HH;
    for (int idx = tid; idx < HH * HH; idx += NT)
      Wt_i[idx % HH][idx / HH] = Wi[idx];          // [j][k] -> [k][j]
  }
  {
    const float* Wh = Whh + (size_t)layer * HH * HH;
    for (int idx = tid; idx < HH * HH; idx += NT)
      Wt_h[idx % HH][idx / HH] = Wh[idx];
  }
  for (int idx = tid; idx < BC * HH; idx += NT)
    hbuf[idx / HH][idx % HH] =
        h0[((size_t)layer * BBS + chunk * BC + idx / HH) * HH + idx % HH];
  __syncthreads();

  // ---- flags / ring pointers ----
  int* prog_in  = (layer > 0)      ? wsi + flag_idx(layer - 1, chunk)        : nullptr;
  int* cons_in  = (layer > 0)      ? wsi + 8192 + flag_idx(layer - 1, chunk) : nullptr;
  int* prog_out = (layer < NL - 1) ? wsi + flag_idx(layer, chunk)            : nullptr;
  int* cons_out = (layer < NL - 1) ? wsi + 8192 + flag_idx(layer, chunk)     : nullptr;
  const size_t slot_sz = (size_t)BC * HH;  // 3200 floats
  float* ring_in  = (layer > 0)      ? ring + (size_t)((layer - 1) * NB + chunk) * RDv * slot_sz : nullptr;
  float* ring_out = (layer < NL - 1) ? ring + (size_t)(layer * NB + chunk) * RDv * slot_sz       : nullptr;

  // compute-tile coords: lhalf 0 -> h@Whh^T, 1 -> inp@Wih^T; 8b x 4j tile
  const int lhalf = tid >> 7;            // 0 or 1
  const int ctid  = tid & 127;
  const int jt = ctid & 31, bt = ctid >> 5;
  const int j0 = jt * 4,    b0 = bt * 8;

  float br[4], w0r[4], w9r[4];
  #pragma unroll
  for (int jj = 0; jj < 4; ++jj) {
    br[jj]  = bias[j0 + jj];
    w0r[jj] = wi0s[j0 + jj];
    w9r[jj] = wouts[j0 + jj];
  }
  const float boutv = bout[0];

  float4 hn[8];          // hnew (half0); doubles as deferred ring-store payload
  float  dso[8];         // deferred layer-9 outputs
  float  px = 0.f;       // layer-0 x prefetch
  bool have_ring_def = false, have_out_def = false;

  for (int t = 0; t < TTS; ++t) {
    const bool batch_start = (t & Km) == 0;
    const bool batch_last  = (t & Km) == Km;

    // ---- batch boundary: wait, acquire, exposed staging of slot t ----
    if (batch_start) {
      if (tid == 0) {
        if (layer > 0) {
          while (__hip_atomic_load(prog_in, __ATOMIC_RELAXED, __HIP_MEMORY_SCOPE_AGENT) < t + Kv)
            __builtin_amdgcn_s_sleep(1);
          (void)__hip_atomic_load(prog_in, __ATOMIC_ACQUIRE, __HIP_MEMORY_SCOPE_AGENT);
        }
        if (layer < NL - 1 && t + Kv > RDv) {
          while (__hip_atomic_load(cons_out, __ATOMIC_RELAXED, __HIP_MEMORY_SCOPE_AGENT) < t + Kv - RDv)
            __builtin_amdgcn_s_sleep(1);
        }
      }
      __syncthreads();
      if (layer > 0) {
        const float* src = ring_in + (size_t)(t & RDm) * slot_sz;
        int i0 = tid * 4;
        float4 q0 = *(const float4*)(src + i0);
        float4 q1 = *(const float4*)(src + i0 + 1024);
        float4 q2 = *(const float4*)(src + i0 + 2048);
        float4 q3 = {};
        if (tid < 32) q3 = *(const float4*)(src + i0 + 3072);
        *(float4*)&ibuf[i0 / HH][i0 % HH] = q0;
        *(float4*)&ibuf[(i0 + 1024) / HH][(i0 + 1024) % HH] = q1;
        *(float4*)&ibuf[(i0 + 2048) / HH][(i0 + 2048) % HH] = q2;
        if (tid < 32) *(float4*)&ibuf[(i0 + 3072) / HH][(i0 + 3072) % HH] = q3;
      } else if (t == 0) {
        if (tid < BC) xin[tid] = x[(size_t)(chunk * BC + tid) * TTS];
      }
      __syncthreads();
    }

    // ---- issue deferred global stores from step t-1 (drain at barrier B) ----
    if (have_ring_def) {
      if (jt < 25) {
        float* dst = ring_out + (size_t)((t - 1) & RDm) * slot_sz;
        #pragma unroll
        for (int bb = 0; bb < 8; ++bb)
          *(float4*)(dst + (size_t)(b0 + bb) * HH + j0) = hn[bb];
      }
      have_ring_def = false;
    }
    if (have_out_def) {
      if (lhalf == 0 && jt == 0) {
        #pragma unroll
        for (int bb = 0; bb < 8; ++bb)
          out[(size_t)(chunk * BC + b0 + bb) * TTS + (t - 1)] = dso[bb];
      }
      have_out_def = false;
    }

    // ---- issue prefetch of inp_{t+1} (consumed after barrier B) ----
    float4 p0 = {}, p1 = {}, p2 = {}, p3 = {};
    bool pre = false;
    if (layer > 0) {
      if (!batch_last && t + 1 < TTS) {
        const float* src = ring_in + (size_t)((t + 1) & RDm) * slot_sz;
        int i0 = tid * 4;
        p0 = *(const float4*)(src + i0);
        p1 = *(const float4*)(src + i0 + 1024);
        p2 = *(const float4*)(src + i0 + 2048);
        if (tid < 32) p3 = *(const float4*)(src + i0 + 3072);
        pre = true;
      }
    } else {
      if (t + 1 < TTS && tid < BC) px = x[(size_t)(chunk * BC + tid) * TTS + (t + 1)];
    }

    // ---- compute: this half's matmul partial, 8b x 4j tile ----
    float acc[8][4];
    #pragma unroll
    for (int bb = 0; bb < 8; ++bb)
      #pragma unroll
      for (int jj = 0; jj < 4; ++jj) acc[bb][jj] = 0.f;

    float xbv[8];
    if (layer == 0 && lhalf == 0) {
      #pragma unroll
      for (int bb = 0; bb < 8; ++bb) xbv[bb] = xin[b0 + bb];  // read before overwrite
    }

    if (lhalf == 0 || layer > 0) {
      const float (*W)[HP] = lhalf ? Wt_i : Wt_h;
      const float (*A)[HP] = lhalf ? ibuf : hbuf;
      for (int k = 0; k < HH; k += 4) {
        float4 wv[4];
        #pragma unroll
        for (int i = 0; i < 4; ++i) wv[i] = *(const float4*)&W[k + i][j0];
        #pragma unroll
        for (int bb = 0; bb < 8; ++bb) {
          float4 av = *(const float4*)&A[b0 + bb][k];
          const float* ap = (const float*)&av;
          #pragma unroll
          for (int i = 0; i < 4; ++i) {
            const float* wp = (const float*)&wv[i];
            #pragma unroll
            for (int jj = 0; jj < 4; ++jj) acc[bb][jj] += ap[i] * wp[jj];
          }
        }
      }
    }

    // half1 publishes partials for half0 to merge
    if (lhalf == 1 && layer > 0) {
      #pragma unroll
      for (int bb = 0; bb < 8; ++bb)
        *(float4*)&pbuf[b0 + bb][j0] =
            make_float4(acc[bb][0], acc[bb][1], acc[bb][2], acc[bb][3]);
    }
    __syncthreads();   // barrier B: partials visible; prefetch + deferred stores drained

    // ---- half0 finalize: merge partials, bias, tanh ----
    if (lhalf == 0) {
      #pragma unroll
      for (int bb = 0; bb < 8; ++bb) {
        float4 pv = {};
        if (layer > 0) pv = *(const float4*)&pbuf[b0 + bb][j0];
        float xw = (layer == 0) ? xbv[bb] : 0.f;
        float v0 = acc[bb][0] + pv.x + br[0] + xw * w0r[0];
        float v1 = acc[bb][1] + pv.y + br[1] + xw * w0r[1];
        float v2 = acc[bb][2] + pv.z + br[2] + xw * w0r[2];
        float v3 = acc[bb][3] + pv.w + br[3] + xw * w0r[3];
        hn[bb] = make_float4(fast_tanh(v0), fast_tanh(v1), fast_tanh(v2), fast_tanh(v3));
      }
      if (layer == NL - 1) {      // shfl-reduce out[b] across 32 j-lanes
        #pragma unroll
        for (int bb = 0; bb < 8; ++bb) {
          float s = hn[bb].x * w9r[0] + hn[bb].y * w9r[1] +
                    hn[bb].z * w9r[2] + hn[bb].w * w9r[3];
          #pragma unroll
          for (int m = 1; m < 32; m <<= 1) s += __shfl_xor(s, m, 32);
          dso[bb] = s + boutv;
        }
      }
      // batch-last ring store cannot be deferred past the flag publish
      if (layer < NL - 1 && batch_last && jt < 25) {
        float* dst = ring_out + (size_t)(t & RDm) * slot_sz;
        #pragma unroll
        for (int bb = 0; bb < 8; ++bb)
          *(float4*)(dst + (size_t)(b0 + bb) * HH + j0) = hn[bb];
      }
      // write recurrent state for t+1
      #pragma unroll
      for (int bb = 0; bb < 8; ++bb)
        *(float4*)&hbuf[b0 + bb][j0] = hn[bb];
      if (t == TTS - 1 && jt < 25) {   // final hidden state (once)
        #pragma unroll
        for (int bb = 0; bb < 8; ++bb)
          *(float4*)(out + (size_t)BBS * TTS +
                     ((size_t)layer * BBS + chunk * BC + b0 + bb) * HH + j0) = hn[bb];
      }
    }

    // ---- stage prefetched inp_{t+1} into LDS ----
    if (pre) {
      int i0 = tid * 4;
      *(float4*)&ibuf[i0 / HH][i0 % HH] = p0;
      *(float4*)&ibuf[(i0 + 1024) / HH][(i0 + 1024) % HH] = p1;
      *(float4*)&ibuf[(i0 + 2048) / HH][(i0 + 2048) % HH] = p2;
      if (tid < 32) *(float4*)&ibuf[(i0 + 3072) / HH][(i0 + 3072) % HH] = p3;
    }
    if (layer == 0 && t + 1 < TTS && tid < BC) xin[tid] = px;

    __syncthreads();   // barrier A: hbuf/ibuf/xin visible; batch-last stores drained

    // ---- flags (once per batch) ----
    if (batch_last && tid == 0) {
      if (layer < NL - 1)
        __hip_atomic_store(prog_out, t + 1, __ATOMIC_RELEASE, __HIP_MEMORY_SCOPE_AGENT);
      if (layer > 0)
        __hip_atomic_store(cons_in, t + 1, __ATOMIC_RELAXED, __HIP_MEMORY_SCOPE_AGENT);
    }

    // ---- set deferrals for step t+1 ----
    if (lhalf == 0 && layer < NL - 1 && !batch_last) have_ring_def = true;
    if (lhalf == 0 && layer == NL - 1 && t < TTS - 1) have_out_def = true;
  }

  // flush last layer-9 outputs (t = TTS-1)
  if (layer == NL - 1 && lhalf == 0 && jt == 0) {
    #pragma unroll
    for (int bb = 0; bb < 8; ++bb)
      out[(size_t)(chunk * BC + b0 + bb) * TTS + (TTS - 1)] = dso[bb];
  }
}

extern "C" void kernel_launch(void* const* d_in, const int* in_sizes, int n_in,
                              void* d_out, int out_size, void* d_ws, size_t ws_size,
                              hipStream_t stream) {
  const float* x    = (const float*)d_in[0];
  const float* h0   = (const float*)d_in[1];
  const float* Wih0 = (const float*)d_in[2];
  const float* Wih  = (const float*)d_in[3];
  const float* Whh  = (const float*)d_in[4];
  const float* bih  = (const float*)d_in[5];
  const float* bhh  = (const float*)d_in[6];
  const float* Wout = (const float*)d_in[7];
  const float* bout = (const float*)d_in[8];
  float* out = (float*)d_out;

  int*   wsi  = (int*)d_ws;
  float* ring = (float*)((char*)d_ws + 65536);

  // Pick deepest ring that fits ws: ring bytes = 144 * RD * 12800
  const size_t slot_bytes = (size_t)BC * HH * 4;   // 12800
  int RDv = 16;
  while (RDv > 2 && 65536 + (size_t)(NL - 1) * NB * RDv * slot_bytes > ws_size)
    RDv >>= 1;
  int Kv = RDv / 2;   // double-buffered batches

  hipLaunchKernelGGL(init_ws_kernel, dim3(64), dim3(256), 0, stream, wsi);
  hipLaunchKernelGGL(rnn_pipe, dim3(NL * NB), dim3(NT), 0, stream,
                     x, h0, Wih0, Wih, Whh, bih, bhh, Wout, bout, out, ring, wsi,
                     Kv, RDv);
}

// Round 5
// 2985.668 us; speedup vs baseline: 2.3936x; 1.4014x over previous
//
#include <hip/hip_runtime.h>

// Multi-layer tanh RNN, layer-pipelined persistent kernel.
// R5 = R4 with compile fix (vector elements can't bind to non-const refs;
// decompose via scalar temps). Theory unchanged:
// R3 was LDS-issue-bound (1200 b128 wave-instr/step ~14.4k cyc) + FMA-wall
// (6.4k cyc) with 1 wave/SIMD. Both matmuls fused into one K=256 (padded)
// GEMM done with mfma_f32_16x16x32_bf16, fp32 operands split into 3 bf16
// planes (exact truncation split; 6 plane-products ~ fp32 accuracy).
// Weights: decomposed ONCE into B-fragment registers (192 VGPR/wave) ->
// zero weight LDS traffic per step. Acts: read fp32 from LDS (32 b128/lane),
// decomposed on the fly (~2.2k VALU cyc, overlaps MFMA pipe).
// Pipeline/flag protocol identical to R2/R3 (proven).
// Grid = 10*16 = 160 blocks, 1 block/CU, LDS ~36KB.

#define HH   100   // hidden
#define HS   132   // padded LDS row stride (132 mod 32 = 4 -> 2-way banks)
#define NL   10    // layers
#define BBS  512   // batch
#define TTS  512   // time
#define NB   16    // batch chunks
#define BC   32    // batch per chunk
#define NT   256   // threads per block

typedef __attribute__((ext_vector_type(8))) short short8;
typedef __attribute__((ext_vector_type(4))) float f32x4;
typedef __attribute__((ext_vector_type(4))) unsigned int u32x4;

__global__ void init_ws_kernel(int* wsi) {
  int i = blockIdx.x * blockDim.x + threadIdx.x;
  if (i < 16384) wsi[i] = 0;   // zero both flag regions (64KB)
}

__device__ __forceinline__ int flag_idx(int iface, int chunk) {
  return (iface * NB + chunk) * 16;
}

__device__ __forceinline__ float fast_tanh(float v) {
  float e = __expf(2.0f * v);
  return 1.0f - 2.0f * __builtin_amdgcn_rcpf(e + 1.0f);
}

__device__ __forceinline__ unsigned pack_hi(unsigned a, unsigned b) {
  return (a >> 16) | (b & 0xFFFF0000u);
}

// Split fp32 pair into 3 packed bf16 planes (exact truncation split):
// x = bf(p1) + bf(p2) + bf(p3) to ~2^-27 relative.
__device__ __forceinline__ void decomp_pair(float x0, float x1,
                                            unsigned& p1, unsigned& p2, unsigned& p3) {
  unsigned u0 = __float_as_uint(x0), u1 = __float_as_uint(x1);
  p1 = pack_hi(u0, u1);
  float r0 = x0 - __uint_as_float(u0 & 0xFFFF0000u);
  float r1 = x1 - __uint_as_float(u1 & 0xFFFF0000u);
  unsigned v0 = __float_as_uint(r0), v1 = __float_as_uint(r1);
  p2 = pack_hi(v0, v1);
  float s0 = r0 - __uint_as_float(v0 & 0xFFFF0000u);
  float s1 = r1 - __uint_as_float(v1 & 0xFFFF0000u);
  p3 = pack_hi(__float_as_uint(s0), __float_as_uint(s1));
}

// 8 consecutive fp32 -> three short8 bf16 fragments (element j == k-offset j)
__device__ __forceinline__ void build_planes(f32x4 lo, f32x4 hi,
                                             short8& A1, short8& A2, short8& A3) {
  u32x4 w1, w2, w3;
  unsigned a, b, c;
  decomp_pair(lo[0], lo[1], a, b, c); w1[0] = a; w2[0] = b; w3[0] = c;
  decomp_pair(lo[2], lo[3], a, b, c); w1[1] = a; w2[1] = b; w3[1] = c;
  decomp_pair(hi[0], hi[1], a, b, c); w1[2] = a; w2[2] = b; w3[2] = c;
  decomp_pair(hi[2], hi[3], a, b, c); w1[3] = a; w2[3] = b; w3[3] = c;
  A1 = __builtin_bit_cast(short8, w1);
  A2 = __builtin_bit_cast(short8, w2);
  A3 = __builtin_bit_cast(short8, w3);
}

__global__ __launch_bounds__(NT, 1) void rnn_pipe(
    const float* __restrict__ x,     // [B,T,1]
    const float* __restrict__ h0,    // [L,B,H]
    const float* __restrict__ Wih0,  // [H,1]
    const float* __restrict__ Wih,   // [L-1,H,H]
    const float* __restrict__ Whh,   // [L,H,H]
    const float* __restrict__ bih,   // [L,H]
    const float* __restrict__ bhh,   // [L,H]
    const float* __restrict__ Wout,  // [1,H]
    const float* __restrict__ bout,  // [1]
    float* __restrict__ out,         // [B*T] outs ++ [L*B*H] h_final
    float* __restrict__ ring,
    int*   __restrict__ wsi,
    int Kv, int RDv)
{
  const int layer = blockIdx.x / NB;
  const int chunk = blockIdx.x % NB;
  const int tid   = threadIdx.x;
  const int Km = Kv - 1, RDm = RDv - 1;

  const int wave = tid >> 6, lane = tid & 63;
  const int quad = lane >> 4, lp = lane & 15;

  // LDS ~ 2*32*132*4 + 3*132*4 + 128 = ~35.5 KB
  __shared__ float hbuf[BC][HS];   // recurrent state fp32, cols >=100 stay 0
  __shared__ float ibuf[BC][HS];   // staged prev-layer input (zeros for layer 0)
  __shared__ float bias[HS];       // b_ih + b_hh, zero-padded
  __shared__ float wi0s[HS];       // W_ih0
  __shared__ float wouts[HS];      // W_out
  __shared__ float xin[BC];        // layer-0 scalar inputs

  // ---- one-time LDS init ----
  for (int i = tid; i < BC * HS; i += NT) { (&hbuf[0][0])[i] = 0.f; (&ibuf[0][0])[i] = 0.f; }
  for (int i = tid; i < HS; i += NT) {
    bias[i]  = (i < HH) ? (bih[layer * HH + i] + bhh[layer * HH + i]) : 0.f;
    wi0s[i]  = (i < HH) ? Wih0[i] : 0.f;
    wouts[i] = (i < HH) ? Wout[i] : 0.f;
  }
  __syncthreads();
  for (int idx = tid; idx < BC * HH; idx += NT)
    hbuf[idx / HH][idx % HH] =
        h0[((size_t)layer * BBS + chunk * BC + idx / HH) * HH + idx % HH];
  __syncthreads();

  // ---- B-fragments in registers: fused W = [Whh (k 0..99) ; Wih (k 128..227)]
  // B[n=lp + nt*16][k = kc*32 + quad*8 + j], 3 bf16 planes. 192 VGPRs.
  short8 Bf[8][2][3];
  #pragma unroll
  for (int kc = 0; kc < 8; ++kc) {
    #pragma unroll
    for (int ntl = 0; ntl < 2; ++ntl) {
      const int n = wave * 32 + ntl * 16 + lp;
      f32x4 wlo = {}, whi = {};
      #pragma unroll
      for (int j = 0; j < 8; ++j) {
        const int k = kc * 32 + quad * 8 + j;
        float w = 0.f;
        if (kc < 4) {
          if (k < HH && n < HH) w = Whh[(size_t)layer * HH * HH + n * HH + k];
        } else {
          const int kk = k - 128;
          if (layer > 0 && kk >= 0 && kk < HH && n < HH)
            w = Wih[(size_t)(layer - 1) * HH * HH + n * HH + kk];
        }
        if (j < 4) wlo[j] = w; else whi[j - 4] = w;
      }
      build_planes(wlo, whi, Bf[kc][ntl][0], Bf[kc][ntl][1], Bf[kc][ntl][2]);
    }
  }

  // ---- flags / ring pointers (R2/R3 proven protocol) ----
  int* prog_in  = (layer > 0)      ? wsi + flag_idx(layer - 1, chunk)        : nullptr;
  int* cons_in  = (layer > 0)      ? wsi + 8192 + flag_idx(layer - 1, chunk) : nullptr;
  int* prog_out = (layer < NL - 1) ? wsi + flag_idx(layer, chunk)            : nullptr;
  int* cons_out = (layer < NL - 1) ? wsi + 8192 + flag_idx(layer, chunk)     : nullptr;
  const size_t slot_sz = (size_t)BC * HH;  // 3200 floats
  float* ring_in  = (layer > 0)      ? ring + (size_t)((layer - 1) * NB + chunk) * RDv * slot_sz : nullptr;
  float* ring_out = (layer < NL - 1) ? ring + (size_t)(layer * NB + chunk) * RDv * slot_sz       : nullptr;

  const int jcv[2] = { wave * 32 + lp, wave * 32 + 16 + lp };   // C columns
  const float br[2]  = { bias[jcv[0]], bias[jcv[1]] };
  const float w0r[2] = { wi0s[jcv[0]], wi0s[jcv[1]] };
  const float boutv = bout[0];

  f32x4 hreg[2][2];          // step-t h values in C layout (deferred stores)
  float dso = 0.f;           // deferred layer-9 output (1/thread)
  float px = 0.f;
  bool have_ring_def = false, have_out_def = false;

  for (int t = 0; t < TTS; ++t) {
    const bool batch_start = (t & Km) == 0;
    const bool batch_last  = (t & Km) == Km;

    // ---- batch boundary: wait + exposed staging of slot t ----
    if (batch_start) {
      if (tid == 0) {
        if (layer > 0) {
          while (__hip_atomic_load(prog_in, __ATOMIC_RELAXED, __HIP_MEMORY_SCOPE_AGENT) < t + Kv)
            __builtin_amdgcn_s_sleep(1);
          (void)__hip_atomic_load(prog_in, __ATOMIC_ACQUIRE, __HIP_MEMORY_SCOPE_AGENT);
        }
        if (layer < NL - 1 && t + Kv > RDv) {
          while (__hip_atomic_load(cons_out, __ATOMIC_RELAXED, __HIP_MEMORY_SCOPE_AGENT) < t + Kv - RDv)
            __builtin_amdgcn_s_sleep(1);
        }
      }
      __syncthreads();
      if (layer > 0) {
        const float* src = ring_in + (size_t)(t & RDm) * slot_sz;
        int i0 = tid * 4;
        f32x4 q0 = *(const f32x4*)(src + i0);
        f32x4 q1 = *(const f32x4*)(src + i0 + 1024);
        f32x4 q2 = *(const f32x4*)(src + i0 + 2048);
        f32x4 q3 = {};
        if (tid < 32) q3 = *(const f32x4*)(src + i0 + 3072);
        *(f32x4*)&ibuf[i0 / HH][i0 % HH] = q0;
        *(f32x4*)&ibuf[(i0 + 1024) / HH][(i0 + 1024) % HH] = q1;
        *(f32x4*)&ibuf[(i0 + 2048) / HH][(i0 + 2048) % HH] = q2;
        if (tid < 32) *(f32x4*)&ibuf[(i0 + 3072) / HH][(i0 + 3072) % HH] = q3;
      } else if (t == 0) {
        if (tid < BC) xin[tid] = x[(size_t)(chunk * BC + tid) * TTS];
      }
      __syncthreads();
    }

    // ---- issue deferred stores from step t-1 ----
    if (have_ring_def) {
      float* dst = ring_out + (size_t)((t - 1) & RDm) * slot_sz;
      #pragma unroll
      for (int mt = 0; mt < 2; ++mt)
        #pragma unroll
        for (int ntl = 0; ntl < 2; ++ntl)
          if (jcv[ntl] < HH)
            #pragma unroll
            for (int r = 0; r < 4; ++r)
              dst[(size_t)(mt * 16 + quad * 4 + r) * HH + jcv[ntl]] = hreg[mt][ntl][r];
      have_ring_def = false;
    }
    if (have_out_def) {
      if ((tid & 7) == 0)
        out[(size_t)(chunk * BC + (tid >> 3)) * TTS + (t - 1)] = dso;
      have_out_def = false;
    }

    // ---- prefetch inp_{t+1} into regs (consumed after barrier B) ----
    f32x4 p0 = {}, p1 = {}, p2 = {}, p3 = {};
    bool pre = false;
    if (layer > 0) {
      if (!batch_last && t + 1 < TTS) {
        const float* src = ring_in + (size_t)((t + 1) & RDm) * slot_sz;
        int i0 = tid * 4;
        p0 = *(const f32x4*)(src + i0);
        p1 = *(const f32x4*)(src + i0 + 1024);
        p2 = *(const f32x4*)(src + i0 + 2048);
        if (tid < 32) p3 = *(const f32x4*)(src + i0 + 3072);
        pre = true;
      }
    } else {
      if (t + 1 < TTS && tid < BC) px = x[(size_t)(chunk * BC + tid) * TTS + (t + 1)];
    }

    // ---- MFMA compute: acc[mt][ntl] = [h|inp] @ Wfused^T (bf16x3, 6 passes) ----
    f32x4 acc[2][2] = {};
    #pragma unroll
    for (int kc = 0; kc < 8; ++kc) {
      short8 A1[2], A2[2], A3[2];
      #pragma unroll
      for (int mt = 0; mt < 2; ++mt) {
        const int m = mt * 16 + lp;
        const float* rp = (kc < 4) ? &hbuf[m][kc * 32 + quad * 8]
                                   : &ibuf[m][(kc - 4) * 32 + quad * 8];
        f32x4 qlo = *(const f32x4*)rp;
        f32x4 qhi = *(const f32x4*)(rp + 4);
        build_planes(qlo, qhi, A1[mt], A2[mt], A3[mt]);
      }
      // plane pairs, smallest-magnitude first: (3,1),(1,3),(2,2),(2,1),(1,2),(1,1)
      #pragma unroll
      for (int p = 0; p < 6; ++p) {
        const int pa[6] = {2, 0, 1, 1, 0, 0};
        const int pb[6] = {0, 2, 1, 0, 1, 0};
        #pragma unroll
        for (int mt = 0; mt < 2; ++mt) {
          const short8& Ax = (pa[p] == 0) ? A1[mt] : (pa[p] == 1) ? A2[mt] : A3[mt];
          #pragma unroll
          for (int ntl = 0; ntl < 2; ++ntl)
            acc[mt][ntl] = __builtin_amdgcn_mfma_f32_16x16x32_bf16(
                Ax, Bf[kc][ntl][pb[p]], acc[mt][ntl], 0, 0, 0);
        }
      }
    }

    __syncthreads();   // barrier B: all hbuf/ibuf reads done; prefetch in flight

    // ---- epilogue: bias (+x*w0 for layer0), tanh, write hbuf ----
    #pragma unroll
    for (int mt = 0; mt < 2; ++mt) {
      #pragma unroll
      for (int ntl = 0; ntl < 2; ++ntl) {
        #pragma unroll
        for (int r = 0; r < 4; ++r) {
          const int m = mt * 16 + quad * 4 + r;
          float v = acc[mt][ntl][r] + br[ntl];
          if (layer == 0) v += xin[m] * w0r[ntl];
          float h = fast_tanh(v);
          hreg[mt][ntl][r] = h;
          if (jcv[ntl] < HH) hbuf[m][jcv[ntl]] = h;
        }
      }
    }

    // batch-last ring store cannot be deferred past the flag publish
    if (layer < NL - 1 && batch_last) {
      float* dst = ring_out + (size_t)(t & RDm) * slot_sz;
      #pragma unroll
      for (int mt = 0; mt < 2; ++mt)
        #pragma unroll
        for (int ntl = 0; ntl < 2; ++ntl)
          if (jcv[ntl] < HH)
            #pragma unroll
            for (int r = 0; r < 4; ++r)
              dst[(size_t)(mt * 16 + quad * 4 + r) * HH + jcv[ntl]] = hreg[mt][ntl][r];
    }

    // ---- stage prefetched inp_{t+1} into LDS ----
    if (pre) {
      int i0 = tid * 4;
      *(f32x4*)&ibuf[i0 / HH][i0 % HH] = p0;
      *(f32x4*)&ibuf[(i0 + 1024) / HH][(i0 + 1024) % HH] = p1;
      *(f32x4*)&ibuf[(i0 + 2048) / HH][(i0 + 2048) % HH] = p2;
      if (tid < 32) *(f32x4*)&ibuf[(i0 + 3072) / HH][(i0 + 3072) % HH] = p3;
    }
    if (layer == 0 && t + 1 < TTS && tid < BC) xin[tid] = px;

    __syncthreads();   // barrier A: hbuf/ibuf/xin visible; stores drained

    // ---- flags (once per batch) ----
    if (batch_last && tid == 0) {
      if (layer < NL - 1)
        __hip_atomic_store(prog_out, t + 1, __ATOMIC_RELEASE, __HIP_MEMORY_SCOPE_AGENT);
      if (layer > 0)
        __hip_atomic_store(cons_in, t + 1, __ATOMIC_RELAXED, __HIP_MEMORY_SCOPE_AGENT);
    }

    // ---- layer-9 output dot (reads fresh hbuf, post barrier A) ----
    if (layer == NL - 1) {
      const int b = tid >> 3, seg = tid & 7;
      float s = 0.f;
      #pragma unroll
      for (int jj = 0; jj < 13; ++jj) {
        const int j = seg * 13 + jj;
        if (j < HH) s += hbuf[b][j] * wouts[j];
      }
      s += __shfl_xor(s, 1, 8);
      s += __shfl_xor(s, 2, 8);
      s += __shfl_xor(s, 4, 8);
      dso = s + boutv;
      if (t < TTS - 1) have_out_def = true;
    }
    if (layer < NL - 1 && !batch_last) have_ring_def = true;
  }

  // flush last layer-9 outputs (t = TTS-1)
  if (layer == NL - 1 && (tid & 7) == 0)
    out[(size_t)(chunk * BC + (tid >> 3)) * TTS + (TTS - 1)] = dso;

  // final hidden state
  for (int i = tid; i < BC * HH; i += NT)
    out[(size_t)BBS * TTS + ((size_t)layer * BBS + chunk * BC + i / HH) * HH + i % HH] =
        hbuf[i / HH][i % HH];
}

extern "C" void kernel_launch(void* const* d_in, const int* in_sizes, int n_in,
                              void* d_out, int out_size, void* d_ws, size_t ws_size,
                              hipStream_t stream) {
  const float* x    = (const float*)d_in[0];
  const float* h0   = (const float*)d_in[1];
  const float* Wih0 = (const float*)d_in[2];
  const float* Wih  = (const float*)d_in[3];
  const float* Whh  = (const float*)d_in[4];
  const float* bih  = (const float*)d_in[5];
  const float* bhh  = (const float*)d_in[6];
  const float* Wout = (const float*)d_in[7];
  const float* bout = (const float*)d_in[8];
  float* out = (float*)d_out;

  int*   wsi  = (int*)d_ws;
  float* ring = (float*)((char*)d_ws + 65536);

  const size_t slot_bytes = (size_t)BC * HH * 4;   // 12800
  int RDv = 16;
  while (RDv > 2 && 65536 + (size_t)(NL - 1) * NB * RDv * slot_bytes > ws_size)
    RDv >>= 1;
  int Kv = RDv / 2;

  hipLaunchKernelGGL(init_ws_kernel, dim3(64), dim3(256), 0, stream, wsi);
  hipLaunchKernelGGL(rnn_pipe, dim3(NL * NB), dim3(NT), 0, stream,
                     x, h0, Wih0, Wih, Whh, bih, bhh, Wout, bout, out, ring, wsi,
                     Kv, RDv);
}

// Round 6
// 2436.087 us; speedup vs baseline: 2.9336x; 1.2256x over previous
//
#include <hip/hip_runtime.h>

// Multi-layer tanh RNN, layer-pipelined persistent kernel.
// R6: bf16x2 MFMA (3 plane-products; R5's 6-product bf16x3 showed zero absmax
// cost -> spend the accuracy margin), double-buffered hbuf/ibuf/xin with ONE
// __syncthreads per step (was 2), K=16/RD=32 flag batching (half the
// agent-scope wbl2/inv events), nontemporal ring stores.
// Weights stay resident in VGPRs as pre-decomposed B-fragments (128 VGPR).
// Grid = 10*16 = 160 blocks, 1 block/CU, LDS ~70KB.

#define HH   100   // hidden
#define HS   132   // padded LDS row stride (16B-aligned rows; 2-way banks ok)
#define NL   10    // layers
#define BBS  512   // batch
#define TTS  512   // time
#define NB   16    // batch chunks
#define BC   32    // batch per chunk
#define NT   256   // threads per block

typedef __attribute__((ext_vector_type(8))) short short8;
typedef __attribute__((ext_vector_type(4))) float f32x4;
typedef __attribute__((ext_vector_type(4))) unsigned int u32x4;

__global__ void init_ws_kernel(int* wsi) {
  int i = blockIdx.x * blockDim.x + threadIdx.x;
  if (i < 16384) wsi[i] = 0;   // zero both flag regions (64KB)
}

__device__ __forceinline__ int flag_idx(int iface, int chunk) {
  return (iface * NB + chunk) * 16;
}

__device__ __forceinline__ float fast_tanh(float v) {
  float e = __expf(2.0f * v);
  return 1.0f - 2.0f * __builtin_amdgcn_rcpf(e + 1.0f);
}

__device__ __forceinline__ unsigned pack_hi(unsigned a, unsigned b) {
  return (a >> 16) | (b & 0xFFFF0000u);
}

// Split fp32 pair into 2 packed bf16 planes (exact truncation split):
// x = bf(p1) + bf(p2) to ~2^-16 relative.
__device__ __forceinline__ void decomp2(float x0, float x1,
                                        unsigned& p1, unsigned& p2) {
  unsigned u0 = __float_as_uint(x0), u1 = __float_as_uint(x1);
  p1 = pack_hi(u0, u1);
  float r0 = x0 - __uint_as_float(u0 & 0xFFFF0000u);
  float r1 = x1 - __uint_as_float(u1 & 0xFFFF0000u);
  p2 = pack_hi(__float_as_uint(r0), __float_as_uint(r1));
}

// 8 consecutive fp32 -> two short8 bf16 fragments (element j == k-offset j)
__device__ __forceinline__ void build2(f32x4 lo, f32x4 hi,
                                       short8& A1, short8& A2) {
  u32x4 w1, w2;
  unsigned a, b;
  decomp2(lo[0], lo[1], a, b); w1[0] = a; w2[0] = b;
  decomp2(lo[2], lo[3], a, b); w1[1] = a; w2[1] = b;
  decomp2(hi[0], hi[1], a, b); w1[2] = a; w2[2] = b;
  decomp2(hi[2], hi[3], a, b); w1[3] = a; w2[3] = b;
  A1 = __builtin_bit_cast(short8, w1);
  A2 = __builtin_bit_cast(short8, w2);
}

__global__ __launch_bounds__(NT, 1) void rnn_pipe(
    const float* __restrict__ x,     // [B,T,1]
    const float* __restrict__ h0,    // [L,B,H]
    const float* __restrict__ Wih0,  // [H,1]
    const float* __restrict__ Wih,   // [L-1,H,H]
    const float* __restrict__ Whh,   // [L,H,H]
    const float* __restrict__ bih,   // [L,H]
    const float* __restrict__ bhh,   // [L,H]
    const float* __restrict__ Wout,  // [1,H]
    const float* __restrict__ bout,  // [1]
    float* __restrict__ out,         // [B*T] outs ++ [L*B*H] h_final
    float* __restrict__ ring,
    int*   __restrict__ wsi,
    int Kv, int RDv)
{
  const int layer = blockIdx.x / NB;
  const int chunk = blockIdx.x % NB;
  const int tid   = threadIdx.x;
  const int Km = Kv - 1, RDm = RDv - 1;

  const int wave = tid >> 6, lane = tid & 63;
  const int quad = lane >> 4, lp = lane & 15;

  // LDS ~ 4*32*132*4 + 3*132*4 + 2*128 = ~69.5 KB
  __shared__ float hbuf[2][BC][HS];  // recurrent state fp32 (parity = t&1 read)
  __shared__ float ibuf[2][BC][HS];  // staged prev-layer input
  __shared__ float bias[HS];         // b_ih + b_hh, zero-padded
  __shared__ float wi0s[HS];         // W_ih0
  __shared__ float wouts[HS];        // W_out
  __shared__ float xin[2][BC];       // layer-0 scalar inputs

  // ---- one-time LDS init ----
  for (int i = tid; i < 2 * BC * HS; i += NT) {
    (&hbuf[0][0][0])[i] = 0.f; (&ibuf[0][0][0])[i] = 0.f;
  }
  for (int i = tid; i < HS; i += NT) {
    bias[i]  = (i < HH) ? (bih[layer * HH + i] + bhh[layer * HH + i]) : 0.f;
    wi0s[i]  = (i < HH) ? Wih0[i] : 0.f;
    wouts[i] = (i < HH) ? Wout[i] : 0.f;
  }
  if (tid < 2 * BC) xin[0][tid & 31] = 0.f;
  __syncthreads();
  for (int idx = tid; idx < BC * HH; idx += NT)
    hbuf[0][idx / HH][idx % HH] =
        h0[((size_t)layer * BBS + chunk * BC + idx / HH) * HH + idx % HH];
  __syncthreads();

  // ---- B-fragments in registers: fused W = [Whh (k 0..99) ; Wih (k 128..227)]
  // B[n = wave*32 + ntl*16 + lp][k = kc*32 + quad*8 + j], 2 bf16 planes.
  short8 Bf[8][2][2];   // 128 VGPRs
  #pragma unroll
  for (int kc = 0; kc < 8; ++kc) {
    #pragma unroll
    for (int ntl = 0; ntl < 2; ++ntl) {
      const int n = wave * 32 + ntl * 16 + lp;
      f32x4 wlo = {}, whi = {};
      #pragma unroll
      for (int j = 0; j < 8; ++j) {
        const int k = kc * 32 + quad * 8 + j;
        float w = 0.f;
        if (kc < 4) {
          if (k < HH && n < HH) w = Whh[(size_t)layer * HH * HH + n * HH + k];
        } else {
          const int kk = k - 128;
          if (layer > 0 && kk >= 0 && kk < HH && n < HH)
            w = Wih[(size_t)(layer - 1) * HH * HH + n * HH + kk];
        }
        if (j < 4) wlo[j] = w; else whi[j - 4] = w;
      }
      build2(wlo, whi, Bf[kc][ntl][0], Bf[kc][ntl][1]);
    }
  }

  // ---- flags / ring pointers (proven protocol) ----
  int* prog_in  = (layer > 0)      ? wsi + flag_idx(layer - 1, chunk)        : nullptr;
  int* cons_in  = (layer > 0)      ? wsi + 8192 + flag_idx(layer - 1, chunk) : nullptr;
  int* prog_out = (layer < NL - 1) ? wsi + flag_idx(layer, chunk)            : nullptr;
  int* cons_out = (layer < NL - 1) ? wsi + 8192 + flag_idx(layer, chunk)     : nullptr;
  const size_t slot_sz = (size_t)BC * HH;  // 3200 floats
  float* ring_in  = (layer > 0)      ? ring + (size_t)((layer - 1) * NB + chunk) * RDv * slot_sz : nullptr;
  float* ring_out = (layer < NL - 1) ? ring + (size_t)(layer * NB + chunk) * RDv * slot_sz       : nullptr;

  const int jcv[2] = { wave * 32 + lp, wave * 32 + 16 + lp };   // C columns
  const float br[2]  = { bias[jcv[0]], bias[jcv[1]] };
  const float w0r[2] = { wi0s[jcv[0]], wi0s[jcv[1]] };
  const float boutv = bout[0];

  f32x4 hreg[2][2];          // step-t h values in C layout (deferred stores)
  float dso = 0.f;           // deferred layer-9 output (1/thread)
  float px = 0.f;
  bool have_ring_def = false, have_out_def = false;

  for (int t = 0; t < TTS; ++t) {
    const int par = t & 1, nxt = par ^ 1;
    const bool batch_start = (t & Km) == 0;
    const bool batch_last  = (t & Km) == Km;

    // ---- batch boundary: wait + exposed staging of slot t into parity par ----
    if (batch_start) {
      if (tid == 0) {
        if (layer > 0) {
          while (__hip_atomic_load(prog_in, __ATOMIC_RELAXED, __HIP_MEMORY_SCOPE_AGENT) < t + Kv)
            __builtin_amdgcn_s_sleep(1);
          (void)__hip_atomic_load(prog_in, __ATOMIC_ACQUIRE, __HIP_MEMORY_SCOPE_AGENT);
        }
        if (layer < NL - 1 && t + Kv > RDv) {
          while (__hip_atomic_load(cons_out, __ATOMIC_RELAXED, __HIP_MEMORY_SCOPE_AGENT) < t + Kv - RDv)
            __builtin_amdgcn_s_sleep(1);
        }
      }
      __syncthreads();
      if (layer > 0) {
        const float* src = ring_in + (size_t)(t & RDm) * slot_sz;
        int i0 = tid * 4;
        f32x4 q0 = *(const f32x4*)(src + i0);
        f32x4 q1 = *(const f32x4*)(src + i0 + 1024);
        f32x4 q2 = *(const f32x4*)(src + i0 + 2048);
        f32x4 q3 = {};
        if (tid < 32) q3 = *(const f32x4*)(src + i0 + 3072);
        *(f32x4*)&ibuf[par][i0 / HH][i0 % HH] = q0;
        *(f32x4*)&ibuf[par][(i0 + 1024) / HH][(i0 + 1024) % HH] = q1;
        *(f32x4*)&ibuf[par][(i0 + 2048) / HH][(i0 + 2048) % HH] = q2;
        if (tid < 32) *(f32x4*)&ibuf[par][(i0 + 3072) / HH][(i0 + 3072) % HH] = q3;
      } else if (t == 0) {
        if (tid < BC) xin[0][tid] = x[(size_t)(chunk * BC + tid) * TTS];
      }
      __syncthreads();
    }

    // ---- issue deferred stores from step t-1 ----
    if (have_ring_def) {
      float* dst = ring_out + (size_t)((t - 1) & RDm) * slot_sz;
      #pragma unroll
      for (int mt = 0; mt < 2; ++mt)
        #pragma unroll
        for (int ntl = 0; ntl < 2; ++ntl)
          if (jcv[ntl] < HH)
            #pragma unroll
            for (int r = 0; r < 4; ++r)
              __builtin_nontemporal_store(hreg[mt][ntl][r],
                  dst + (size_t)(mt * 16 + quad * 4 + r) * HH + jcv[ntl]);
      have_ring_def = false;
    }
    if (have_out_def) {
      if ((tid & 7) == 0)
        out[(size_t)(chunk * BC + (tid >> 3)) * TTS + (t - 1)] = dso;
      have_out_def = false;
    }

    // ---- prefetch inp_{t+1} into regs (staged into ibuf[nxt] post-compute) ----
    f32x4 p0 = {}, p1 = {}, p2 = {}, p3 = {};
    bool pre = false;
    if (layer > 0) {
      if (!batch_last && t + 1 < TTS) {
        const float* src = ring_in + (size_t)((t + 1) & RDm) * slot_sz;
        int i0 = tid * 4;
        p0 = *(const f32x4*)(src + i0);
        p1 = *(const f32x4*)(src + i0 + 1024);
        p2 = *(const f32x4*)(src + i0 + 2048);
        if (tid < 32) p3 = *(const f32x4*)(src + i0 + 3072);
        pre = true;
      }
    } else {
      if (t + 1 < TTS && tid < BC) px = x[(size_t)(chunk * BC + tid) * TTS + (t + 1)];
    }

    // ---- MFMA: acc = [h|inp] @ Wfused^T, bf16x2 (3 plane-products) ----
    f32x4 acc[2][2] = {};
    auto mfma_kc = [&](const float (*buf)[HS], int koff, int bfi) {
      short8 A1[2], A2[2];
      #pragma unroll
      for (int mt = 0; mt < 2; ++mt) {
        const float* rp = &buf[mt * 16 + lp][koff + quad * 8];
        f32x4 qlo = *(const f32x4*)rp;
        f32x4 qhi = *(const f32x4*)(rp + 4);
        build2(qlo, qhi, A1[mt], A2[mt]);
      }
      #pragma unroll
      for (int mt = 0; mt < 2; ++mt)
        #pragma unroll
        for (int ntl = 0; ntl < 2; ++ntl) {
          acc[mt][ntl] = __builtin_amdgcn_mfma_f32_16x16x32_bf16(
              A2[mt], Bf[bfi][ntl][0], acc[mt][ntl], 0, 0, 0);   // a2*b1
          acc[mt][ntl] = __builtin_amdgcn_mfma_f32_16x16x32_bf16(
              A1[mt], Bf[bfi][ntl][1], acc[mt][ntl], 0, 0, 0);   // a1*b2
          acc[mt][ntl] = __builtin_amdgcn_mfma_f32_16x16x32_bf16(
              A1[mt], Bf[bfi][ntl][0], acc[mt][ntl], 0, 0, 0);   // a1*b1
        }
    };
    #pragma unroll
    for (int kc = 0; kc < 4; ++kc) mfma_kc(hbuf[par], kc * 32, kc);
    if (layer > 0) {
      #pragma unroll
      for (int kc = 0; kc < 4; ++kc) mfma_kc(ibuf[par], kc * 32, kc + 4);
    }

    // ---- epilogue: bias (+x*w0 for layer0), tanh, write hbuf[nxt] ----
    #pragma unroll
    for (int mt = 0; mt < 2; ++mt) {
      #pragma unroll
      for (int ntl = 0; ntl < 2; ++ntl) {
        #pragma unroll
        for (int r = 0; r < 4; ++r) {
          const int m = mt * 16 + quad * 4 + r;
          float v = acc[mt][ntl][r] + br[ntl];
          if (layer == 0) v += xin[par][m] * w0r[ntl];
          float h = fast_tanh(v);
          hreg[mt][ntl][r] = h;
          if (jcv[ntl] < HH) hbuf[nxt][m][jcv[ntl]] = h;
        }
      }
    }

    // batch-last ring store cannot be deferred past the flag publish
    if (layer < NL - 1 && batch_last) {
      float* dst = ring_out + (size_t)(t & RDm) * slot_sz;
      #pragma unroll
      for (int mt = 0; mt < 2; ++mt)
        #pragma unroll
        for (int ntl = 0; ntl < 2; ++ntl)
          if (jcv[ntl] < HH)
            #pragma unroll
            for (int r = 0; r < 4; ++r)
              __builtin_nontemporal_store(hreg[mt][ntl][r],
                  dst + (size_t)(mt * 16 + quad * 4 + r) * HH + jcv[ntl]);
    }

    // ---- stage prefetched inp_{t+1} into ibuf[nxt] / xin[nxt] ----
    if (pre) {
      int i0 = tid * 4;
      *(f32x4*)&ibuf[nxt][i0 / HH][i0 % HH] = p0;
      *(f32x4*)&ibuf[nxt][(i0 + 1024) / HH][(i0 + 1024) % HH] = p1;
      *(f32x4*)&ibuf[nxt][(i0 + 2048) / HH][(i0 + 2048) % HH] = p2;
      if (tid < 32) *(f32x4*)&ibuf[nxt][(i0 + 3072) / HH][(i0 + 3072) % HH] = p3;
    }
    if (layer == 0 && t + 1 < TTS && tid < BC) xin[nxt][tid] = px;

    __syncthreads();   // single per-step barrier: all LDS writes + stores drained

    // ---- flags (once per batch) ----
    if (batch_last && tid == 0) {
      if (layer < NL - 1)
        __hip_atomic_store(prog_out, t + 1, __ATOMIC_RELEASE, __HIP_MEMORY_SCOPE_AGENT);
      if (layer > 0)
        __hip_atomic_store(cons_in, t + 1, __ATOMIC_RELAXED, __HIP_MEMORY_SCOPE_AGENT);
    }

    // ---- layer-9 output dot (reads fresh hbuf[nxt]) ----
    if (layer == NL - 1) {
      const int b = tid >> 3, seg = tid & 7;
      float s = 0.f;
      #pragma unroll
      for (int jj = 0; jj < 13; ++jj) {
        const int j = seg * 13 + jj;
        if (j < HH) s += hbuf[nxt][b][j] * wouts[j];
      }
      s += __shfl_xor(s, 1, 8);
      s += __shfl_xor(s, 2, 8);
      s += __shfl_xor(s, 4, 8);
      dso = s + boutv;
      if (t < TTS - 1) have_out_def = true;
    }
    if (layer < NL - 1 && !batch_last) have_ring_def = true;
  }

  // flush last layer-9 outputs (t = TTS-1)
  if (layer == NL - 1 && (tid & 7) == 0)
    out[(size_t)(chunk * BC + (tid >> 3)) * TTS + (TTS - 1)] = dso;

  // final hidden state: TTS even -> lives in hbuf[0]
  for (int i = tid; i < BC * HH; i += NT)
    out[(size_t)BBS * TTS + ((size_t)layer * BBS + chunk * BC + i / HH) * HH + i % HH] =
        hbuf[0][i / HH][i % HH];
}

extern "C" void kernel_launch(void* const* d_in, const int* in_sizes, int n_in,
                              void* d_out, int out_size, void* d_ws, size_t ws_size,
                              hipStream_t stream) {
  const float* x    = (const float*)d_in[0];
  const float* h0   = (const float*)d_in[1];
  const float* Wih0 = (const float*)d_in[2];
  const float* Wih  = (const float*)d_in[3];
  const float* Whh  = (const float*)d_in[4];
  const float* bih  = (const float*)d_in[5];
  const float* bhh  = (const float*)d_in[6];
  const float* Wout = (const float*)d_in[7];
  const float* bout = (const float*)d_in[8];
  float* out = (float*)d_out;

  int*   wsi  = (int*)d_ws;
  float* ring = (float*)((char*)d_ws + 65536);

  // Pick deepest ring that fits ws: ring bytes = 144 * RD * 12800
  const size_t slot_bytes = (size_t)BC * HH * 4;   // 12800
  int RDv = 32;
  while (RDv > 2 && 65536 + (size_t)(NL - 1) * NB * RDv * slot_bytes > ws_size)
    RDv >>= 1;
  int Kv = RDv / 2;

  hipLaunchKernelGGL(init_ws_kernel, dim3(64), dim3(256), 0, stream, wsi);
  hipLaunchKernelGGL(rnn_pipe, dim3(NL * NB), dim3(NT), 0, stream,
                     x, h0, Wih0, Wih, Whh, bih, bhh, Wout, bout, out, ring, wsi,
                     Kv, RDv);
}

// Round 7
// 1840.051 us; speedup vs baseline: 3.8839x; 1.3239x over previous
//
#include <hip/hip_runtime.h>

// Multi-layer tanh RNN, layer-pipelined persistent kernel.
// R7: occupancy attack. R6 counters: VALUBusy 18%, MfmaUtil 8%, Occupancy
// 6.7% -> ~2.7us/step of exposed latency with 1 block/CU. Split batch chunks
// in half: NB=32, BC=16, grid=320 at 2 blocks/CU (launch_bounds(256,2),
// LDS ~36KB, VGPR ~120) so a co-resident block fills each block's stall gaps.
// Everything else (bf16x2 MFMA, reg-resident weights, K=16/RD=32 batched
// flags, nt ring stores, single per-step barrier) carried from R6.

#define HH   100   // hidden
#define HS   132   // padded LDS row stride
#define NL   10    // layers
#define BBS  512   // batch
#define TTS  512   // time
#define NB   32    // batch chunks
#define BC   16    // batch per chunk
#define NT   256   // threads per block

typedef __attribute__((ext_vector_type(8))) short short8;
typedef __attribute__((ext_vector_type(4))) float f32x4;
typedef __attribute__((ext_vector_type(4))) unsigned int u32x4;

__global__ void init_ws_kernel(int* wsi) {
  int i = blockIdx.x * blockDim.x + threadIdx.x;
  if (i < 16384) wsi[i] = 0;   // zero both flag regions (64KB)
}

__device__ __forceinline__ int flag_idx(int iface, int chunk) {
  return (iface * NB + chunk) * 16;   // max (8*32+31)*16+15 = 4607 < 8192
}

__device__ __forceinline__ float fast_tanh(float v) {
  float e = __expf(2.0f * v);
  return 1.0f - 2.0f * __builtin_amdgcn_rcpf(e + 1.0f);
}

__device__ __forceinline__ unsigned pack_hi(unsigned a, unsigned b) {
  return (a >> 16) | (b & 0xFFFF0000u);
}

// Split fp32 pair into 2 packed bf16 planes (exact truncation split)
__device__ __forceinline__ void decomp2(float x0, float x1,
                                        unsigned& p1, unsigned& p2) {
  unsigned u0 = __float_as_uint(x0), u1 = __float_as_uint(x1);
  p1 = pack_hi(u0, u1);
  float r0 = x0 - __uint_as_float(u0 & 0xFFFF0000u);
  float r1 = x1 - __uint_as_float(u1 & 0xFFFF0000u);
  p2 = pack_hi(__float_as_uint(r0), __float_as_uint(r1));
}

__device__ __forceinline__ void build2(f32x4 lo, f32x4 hi,
                                       short8& A1, short8& A2) {
  u32x4 w1, w2;
  unsigned a, b;
  decomp2(lo[0], lo[1], a, b); w1[0] = a; w2[0] = b;
  decomp2(lo[2], lo[3], a, b); w1[1] = a; w2[1] = b;
  decomp2(hi[0], hi[1], a, b); w1[2] = a; w2[2] = b;
  decomp2(hi[2], hi[3], a, b); w1[3] = a; w2[3] = b;
  A1 = __builtin_bit_cast(short8, w1);
  A2 = __builtin_bit_cast(short8, w2);
}

__global__ __launch_bounds__(NT, 2) void rnn_pipe(
    const float* __restrict__ x,     // [B,T,1]
    const float* __restrict__ h0,    // [L,B,H]
    const float* __restrict__ Wih0,  // [H,1]
    const float* __restrict__ Wih,   // [L-1,H,H]
    const float* __restrict__ Whh,   // [L,H,H]
    const float* __restrict__ bih,   // [L,H]
    const float* __restrict__ bhh,   // [L,H]
    const float* __restrict__ Wout,  // [1,H]
    const float* __restrict__ bout,  // [1]
    float* __restrict__ out,         // [B*T] outs ++ [L*B*H] h_final
    float* __restrict__ ring,
    int*   __restrict__ wsi,
    int Kv, int RDv)
{
  const int layer = blockIdx.x / NB;
  const int chunk = blockIdx.x % NB;
  const int tid   = threadIdx.x;
  const int Km = Kv - 1, RDm = RDv - 1;
  const int NE = BC * HH;  // 1600 floats per activation slot

  const int wave = tid >> 6, lane = tid & 63;
  const int quad = lane >> 4, lp = lane & 15;

  // LDS ~ 4*16*132*4 + 3*132*4 + 2*64 = ~35.5 KB -> 2 blocks/CU fits easily
  __shared__ float hbuf[2][BC][HS];  // recurrent state fp32 (parity = t&1)
  __shared__ float ibuf[2][BC][HS];  // staged prev-layer input
  __shared__ float bias[HS];
  __shared__ float wi0s[HS];
  __shared__ float wouts[HS];
  __shared__ float xin[2][BC];

  // ---- one-time LDS init ----
  for (int i = tid; i < 2 * BC * HS; i += NT) {
    (&hbuf[0][0][0])[i] = 0.f; (&ibuf[0][0][0])[i] = 0.f;
  }
  for (int i = tid; i < HS; i += NT) {
    bias[i]  = (i < HH) ? (bih[layer * HH + i] + bhh[layer * HH + i]) : 0.f;
    wi0s[i]  = (i < HH) ? Wih0[i] : 0.f;
    wouts[i] = (i < HH) ? Wout[i] : 0.f;
  }
  if (tid < BC) { xin[0][tid] = 0.f; xin[1][tid] = 0.f; }
  __syncthreads();
  for (int idx = tid; idx < NE; idx += NT)
    hbuf[0][idx / HH][idx % HH] =
        h0[((size_t)layer * BBS + chunk * BC + idx / HH) * HH + idx % HH];
  __syncthreads();

  // ---- B-fragments in registers: fused W = [Whh (k 0..99) ; Wih (k 128..227)]
  // B[n = wave*32 + ntl*16 + lp][k = kc*32 + quad*8 + j], 2 bf16 planes.
  short8 Bf[8][2][2];   // 128 VGPRs
  #pragma unroll
  for (int kc = 0; kc < 8; ++kc) {
    #pragma unroll
    for (int ntl = 0; ntl < 2; ++ntl) {
      const int n = wave * 32 + ntl * 16 + lp;
      f32x4 wlo = {}, whi = {};
      #pragma unroll
      for (int j = 0; j < 8; ++j) {
        const int k = kc * 32 + quad * 8 + j;
        float w = 0.f;
        if (kc < 4) {
          if (k < HH && n < HH) w = Whh[(size_t)layer * HH * HH + n * HH + k];
        } else {
          const int kk = k - 128;
          if (layer > 0 && kk >= 0 && kk < HH && n < HH)
            w = Wih[(size_t)(layer - 1) * HH * HH + n * HH + kk];
        }
        if (j < 4) wlo[j] = w; else whi[j - 4] = w;
      }
      build2(wlo, whi, Bf[kc][ntl][0], Bf[kc][ntl][1]);
    }
  }

  // ---- flags / ring pointers (proven protocol) ----
  int* prog_in  = (layer > 0)      ? wsi + flag_idx(layer - 1, chunk)        : nullptr;
  int* cons_in  = (layer > 0)      ? wsi + 8192 + flag_idx(layer - 1, chunk) : nullptr;
  int* prog_out = (layer < NL - 1) ? wsi + flag_idx(layer, chunk)            : nullptr;
  int* cons_out = (layer < NL - 1) ? wsi + 8192 + flag_idx(layer, chunk)     : nullptr;
  const size_t slot_sz = (size_t)NE;  // 1600 floats
  float* ring_in  = (layer > 0)      ? ring + (size_t)((layer - 1) * NB + chunk) * RDv * slot_sz : nullptr;
  float* ring_out = (layer < NL - 1) ? ring + (size_t)(layer * NB + chunk) * RDv * slot_sz       : nullptr;

  const int jcv[2] = { wave * 32 + lp, wave * 32 + 16 + lp };   // C columns
  const float br[2]  = { bias[jcv[0]], bias[jcv[1]] };
  const float w0r[2] = { wi0s[jcv[0]], wi0s[jcv[1]] };
  const float boutv = bout[0];

  f32x4 hreg[2];             // step-t h values in C layout (deferred stores)
  float dso = 0.f;           // deferred layer-9 output
  float px = 0.f;
  bool have_ring_def = false, have_out_def = false;

  for (int t = 0; t < TTS; ++t) {
    const int par = t & 1, nxt = par ^ 1;
    const bool batch_start = (t & Km) == 0;
    const bool batch_last  = (t & Km) == Km;

    // ---- batch boundary: wait + exposed staging of slot t into parity par ----
    if (batch_start) {
      if (tid == 0) {
        if (layer > 0) {
          while (__hip_atomic_load(prog_in, __ATOMIC_RELAXED, __HIP_MEMORY_SCOPE_AGENT) < t + Kv)
            __builtin_amdgcn_s_sleep(1);
          (void)__hip_atomic_load(prog_in, __ATOMIC_ACQUIRE, __HIP_MEMORY_SCOPE_AGENT);
        }
        if (layer < NL - 1 && t + Kv > RDv) {
          while (__hip_atomic_load(cons_out, __ATOMIC_RELAXED, __HIP_MEMORY_SCOPE_AGENT) < t + Kv - RDv)
            __builtin_amdgcn_s_sleep(1);
        }
      }
      __syncthreads();
      if (layer > 0) {
        const float* src = ring_in + (size_t)(t & RDm) * slot_sz;
        int i0 = tid * 4;
        f32x4 q0 = {}, q1 = {};
        if (i0 < NE) q0 = *(const f32x4*)(src + i0);
        if (i0 + 1024 < NE) q1 = *(const f32x4*)(src + i0 + 1024);
        if (i0 < NE) *(f32x4*)&ibuf[par][i0 / HH][i0 % HH] = q0;
        if (i0 + 1024 < NE)
          *(f32x4*)&ibuf[par][(i0 + 1024) / HH][(i0 + 1024) % HH] = q1;
      } else if (t == 0) {
        if (tid < BC) xin[0][tid] = x[(size_t)(chunk * BC + tid) * TTS];
      }
      __syncthreads();
    }

    // ---- issue deferred stores from step t-1 ----
    if (have_ring_def) {
      float* dst = ring_out + (size_t)((t - 1) & RDm) * slot_sz;
      #pragma unroll
      for (int ntl = 0; ntl < 2; ++ntl)
        if (jcv[ntl] < HH)
          #pragma unroll
          for (int r = 0; r < 4; ++r)
            __builtin_nontemporal_store(hreg[ntl][r],
                dst + (size_t)(quad * 4 + r) * HH + jcv[ntl]);
      have_ring_def = false;
    }
    if (have_out_def) {
      if ((tid & 15) == 0)
        out[(size_t)(chunk * BC + (tid >> 4)) * TTS + (t - 1)] = dso;
      have_out_def = false;
    }

    // ---- prefetch inp_{t+1} into regs (staged into ibuf[nxt] post-compute) ----
    f32x4 p0 = {}, p1 = {};
    bool pre = false;
    if (layer > 0) {
      if (!batch_last && t + 1 < TTS) {
        const float* src = ring_in + (size_t)((t + 1) & RDm) * slot_sz;
        int i0 = tid * 4;
        if (i0 < NE) p0 = *(const f32x4*)(src + i0);
        if (i0 + 1024 < NE) p1 = *(const f32x4*)(src + i0 + 1024);
        pre = true;
      }
    } else {
      if (t + 1 < TTS && tid < BC) px = x[(size_t)(chunk * BC + tid) * TTS + (t + 1)];
    }

    // ---- MFMA: acc = [h|inp] @ Wfused^T, bf16x2 (3 plane-products) ----
    f32x4 acc[2] = {};
    auto mfma_kc = [&](const float (*buf)[HS], int koff, int bfi) {
      short8 A1, A2;
      const float* rp = &buf[lp][koff + quad * 8];
      f32x4 qlo = *(const f32x4*)rp;
      f32x4 qhi = *(const f32x4*)(rp + 4);
      build2(qlo, qhi, A1, A2);
      #pragma unroll
      for (int ntl = 0; ntl < 2; ++ntl) {
        acc[ntl] = __builtin_amdgcn_mfma_f32_16x16x32_bf16(
            A2, Bf[bfi][ntl][0], acc[ntl], 0, 0, 0);   // a2*b1
        acc[ntl] = __builtin_amdgcn_mfma_f32_16x16x32_bf16(
            A1, Bf[bfi][ntl][1], acc[ntl], 0, 0, 0);   // a1*b2
        acc[ntl] = __builtin_amdgcn_mfma_f32_16x16x32_bf16(
            A1, Bf[bfi][ntl][0], acc[ntl], 0, 0, 0);   // a1*b1
      }
    };
    #pragma unroll
    for (int kc = 0; kc < 4; ++kc) mfma_kc(hbuf[par], kc * 32, kc);
    if (layer > 0) {
      #pragma unroll
      for (int kc = 0; kc < 4; ++kc) mfma_kc(ibuf[par], kc * 32, kc + 4);
    }

    // ---- epilogue: bias (+x*w0 for layer0), tanh, write hbuf[nxt] ----
    #pragma unroll
    for (int ntl = 0; ntl < 2; ++ntl) {
      #pragma unroll
      for (int r = 0; r < 4; ++r) {
        const int m = quad * 4 + r;
        float v = acc[ntl][r] + br[ntl];
        if (layer == 0) v += xin[par][m] * w0r[ntl];
        float h = fast_tanh(v);
        hreg[ntl][r] = h;
        if (jcv[ntl] < HH) hbuf[nxt][m][jcv[ntl]] = h;
      }
    }

    // batch-last ring store cannot be deferred past the flag publish
    if (layer < NL - 1 && batch_last) {
      float* dst = ring_out + (size_t)(t & RDm) * slot_sz;
      #pragma unroll
      for (int ntl = 0; ntl < 2; ++ntl)
        if (jcv[ntl] < HH)
          #pragma unroll
          for (int r = 0; r < 4; ++r)
            __builtin_nontemporal_store(hreg[ntl][r],
                dst + (size_t)(quad * 4 + r) * HH + jcv[ntl]);
    }

    // ---- stage prefetched inp_{t+1} into ibuf[nxt] / xin[nxt] ----
    if (pre) {
      int i0 = tid * 4;
      if (i0 < NE) *(f32x4*)&ibuf[nxt][i0 / HH][i0 % HH] = p0;
      if (i0 + 1024 < NE)
        *(f32x4*)&ibuf[nxt][(i0 + 1024) / HH][(i0 + 1024) % HH] = p1;
    }
    if (layer == 0 && t + 1 < TTS && tid < BC) xin[nxt][tid] = px;

    __syncthreads();   // single per-step barrier

    // ---- flags (once per batch) ----
    if (batch_last && tid == 0) {
      if (layer < NL - 1)
        __hip_atomic_store(prog_out, t + 1, __ATOMIC_RELEASE, __HIP_MEMORY_SCOPE_AGENT);
      if (layer > 0)
        __hip_atomic_store(cons_in, t + 1, __ATOMIC_RELAXED, __HIP_MEMORY_SCOPE_AGENT);
    }

    // ---- layer-9 output dot (reads fresh hbuf[nxt]) ----
    if (layer == NL - 1) {
      const int b = tid >> 4, seg = tid & 15;
      float s = 0.f;
      #pragma unroll
      for (int jj = 0; jj < 7; ++jj) {
        const int j = seg * 7 + jj;
        if (j < HH) s += hbuf[nxt][b][j] * wouts[j];
      }
      s += __shfl_xor(s, 1, 16);
      s += __shfl_xor(s, 2, 16);
      s += __shfl_xor(s, 4, 16);
      s += __shfl_xor(s, 8, 16);
      dso = s + boutv;
      if (t < TTS - 1) have_out_def = true;
    }
    if (layer < NL - 1 && !batch_last) have_ring_def = true;
  }

  // flush last layer-9 outputs (t = TTS-1)
  if (layer == NL - 1 && (tid & 15) == 0)
    out[(size_t)(chunk * BC + (tid >> 4)) * TTS + (TTS - 1)] = dso;

  // final hidden state: TTS even -> lives in hbuf[0]
  for (int i = tid; i < NE; i += NT)
    out[(size_t)BBS * TTS + ((size_t)layer * BBS + chunk * BC + i / HH) * HH + i % HH] =
        hbuf[0][i / HH][i % HH];
}

extern "C" void kernel_launch(void* const* d_in, const int* in_sizes, int n_in,
                              void* d_out, int out_size, void* d_ws, size_t ws_size,
                              hipStream_t stream) {
  const float* x    = (const float*)d_in[0];
  const float* h0   = (const float*)d_in[1];
  const float* Wih0 = (const float*)d_in[2];
  const float* Wih  = (const float*)d_in[3];
  const float* Whh  = (const float*)d_in[4];
  const float* bih  = (const float*)d_in[5];
  const float* bhh  = (const float*)d_in[6];
  const float* Wout = (const float*)d_in[7];
  const float* bout = (const float*)d_in[8];
  float* out = (float*)d_out;

  int*   wsi  = (int*)d_ws;
  float* ring = (float*)((char*)d_ws + 65536);

  // Pick deepest ring that fits ws: ring bytes = 9*32 * RD * 6400
  const size_t slot_bytes = (size_t)BC * HH * 4;   // 6400
  int RDv = 32;
  while (RDv > 2 && 65536 + (size_t)(NL - 1) * NB * RDv * slot_bytes > ws_size)
    RDv >>= 1;
  int Kv = RDv / 2;

  hipLaunchKernelGGL(init_ws_kernel, dim3(64), dim3(256), 0, stream, wsi);
  hipLaunchKernelGGL(rnn_pipe, dim3(NL * NB), dim3(NT), 0, stream,
                     x, h0, Wih0, Wih, Whh, bih, bhh, Wout, bout, out, ring, wsi,
                     Kv, RDv);
}

// Round 8
// 1796.387 us; speedup vs baseline: 3.9783x; 1.0243x over previous
//
#include <hip/hip_runtime.h>

// Multi-layer tanh RNN, layer-pipelined persistent kernel.
// R8: critical-path latency attack. R7 was ~90% exposed latency per step.
//  - per-step barrier = "s_waitcnt lgkmcnt(0); s_barrier" (asm): LDS ordering
//    kept, but in-flight global ring/out stores are NOT drained per step.
//    They drain once per batch at the RELEASE flag (vmcnt(0) there).
//  - ring stores back to normal (no nontemporal): R6's nt pushed the ring to
//    HBM (FETCH 53->435MB); L2-resident ring = fast store-ack + fast prefetch.
//  - MFMA chains split: acc (hbuf products) + acc2 (ibuf products) -> 4
//    independent 12-deep chains instead of 2x 24-deep, merged in epilogue.
// Carried from R7: NB=32/BC=16, 2 blocks/CU, reg-resident bf16x2 weights,
// K=16/RD=32 batched flags, single per-step barrier, deferred stores.

#define HH   100   // hidden
#define HS   132   // padded LDS row stride
#define NL   10    // layers
#define BBS  512   // batch
#define TTS  512   // time
#define NB   32    // batch chunks
#define BC   16    // batch per chunk
#define NT   256   // threads per block

typedef __attribute__((ext_vector_type(8))) short short8;
typedef __attribute__((ext_vector_type(4))) float f32x4;
typedef __attribute__((ext_vector_type(4))) unsigned int u32x4;

__global__ void init_ws_kernel(int* wsi) {
  int i = blockIdx.x * blockDim.x + threadIdx.x;
  if (i < 16384) wsi[i] = 0;   // zero both flag regions (64KB)
}

__device__ __forceinline__ int flag_idx(int iface, int chunk) {
  return (iface * NB + chunk) * 16;   // max (8*32+31)*16+15 = 4607 < 8192
}

// Barrier that orders LDS only (drains lgkmcnt, leaves global stores in
// flight). Memory clobber stops the compiler moving memory ops across.
__device__ __forceinline__ void lds_barrier() {
  __asm__ __volatile__("s_waitcnt lgkmcnt(0)\n\ts_barrier" ::: "memory");
}
// Control-only barrier (post flag-spin; tid0's ACQUIRE already did its waits).
__device__ __forceinline__ void ctl_barrier() {
  __asm__ __volatile__("s_barrier" ::: "memory");
}

__device__ __forceinline__ float fast_tanh(float v) {
  float e = __expf(2.0f * v);
  return 1.0f - 2.0f * __builtin_amdgcn_rcpf(e + 1.0f);
}

__device__ __forceinline__ unsigned pack_hi(unsigned a, unsigned b) {
  return (a >> 16) | (b & 0xFFFF0000u);
}

// Split fp32 pair into 2 packed bf16 planes (exact truncation split)
__device__ __forceinline__ void decomp2(float x0, float x1,
                                        unsigned& p1, unsigned& p2) {
  unsigned u0 = __float_as_uint(x0), u1 = __float_as_uint(x1);
  p1 = pack_hi(u0, u1);
  float r0 = x0 - __uint_as_float(u0 & 0xFFFF0000u);
  float r1 = x1 - __uint_as_float(u1 & 0xFFFF0000u);
  p2 = pack_hi(__float_as_uint(r0), __float_as_uint(r1));
}

__device__ __forceinline__ void build2(f32x4 lo, f32x4 hi,
                                       short8& A1, short8& A2) {
  u32x4 w1, w2;
  unsigned a, b;
  decomp2(lo[0], lo[1], a, b); w1[0] = a; w2[0] = b;
  decomp2(lo[2], lo[3], a, b); w1[1] = a; w2[1] = b;
  decomp2(hi[0], hi[1], a, b); w1[2] = a; w2[2] = b;
  decomp2(hi[2], hi[3], a, b); w1[3] = a; w2[3] = b;
  A1 = __builtin_bit_cast(short8, w1);
  A2 = __builtin_bit_cast(short8, w2);
}

__global__ __launch_bounds__(NT, 2) void rnn_pipe(
    const float* __restrict__ x,     // [B,T,1]
    const float* __restrict__ h0,    // [L,B,H]
    const float* __restrict__ Wih0,  // [H,1]
    const float* __restrict__ Wih,   // [L-1,H,H]
    const float* __restrict__ Whh,   // [L,H,H]
    const float* __restrict__ bih,   // [L,H]
    const float* __restrict__ bhh,   // [L,H]
    const float* __restrict__ Wout,  // [1,H]
    const float* __restrict__ bout,  // [1]
    float* __restrict__ out,         // [B*T] outs ++ [L*B*H] h_final
    float* __restrict__ ring,
    int*   __restrict__ wsi,
    int Kv, int RDv)
{
  const int layer = blockIdx.x / NB;
  const int chunk = blockIdx.x % NB;
  const int tid   = threadIdx.x;
  const int Km = Kv - 1, RDm = RDv - 1;
  const int NE = BC * HH;  // 1600 floats per activation slot

  const int wave = tid >> 6, lane = tid & 63;
  const int quad = lane >> 4, lp = lane & 15;

  // LDS ~ 4*16*132*4 + 3*132*4 + 2*64 = ~35.5 KB -> 2 blocks/CU
  __shared__ float hbuf[2][BC][HS];  // recurrent state fp32 (parity = t&1)
  __shared__ float ibuf[2][BC][HS];  // staged prev-layer input
  __shared__ float bias[HS];
  __shared__ float wi0s[HS];
  __shared__ float wouts[HS];
  __shared__ float xin[2][BC];

  // ---- one-time LDS init ----
  for (int i = tid; i < 2 * BC * HS; i += NT) {
    (&hbuf[0][0][0])[i] = 0.f; (&ibuf[0][0][0])[i] = 0.f;
  }
  for (int i = tid; i < HS; i += NT) {
    bias[i]  = (i < HH) ? (bih[layer * HH + i] + bhh[layer * HH + i]) : 0.f;
    wi0s[i]  = (i < HH) ? Wih0[i] : 0.f;
    wouts[i] = (i < HH) ? Wout[i] : 0.f;
  }
  if (tid < BC) { xin[0][tid] = 0.f; xin[1][tid] = 0.f; }
  __syncthreads();
  for (int idx = tid; idx < NE; idx += NT)
    hbuf[0][idx / HH][idx % HH] =
        h0[((size_t)layer * BBS + chunk * BC + idx / HH) * HH + idx % HH];
  __syncthreads();

  // ---- B-fragments in registers: fused W = [Whh (k 0..99) ; Wih (k 128..227)]
  short8 Bf[8][2][2];   // 128 VGPRs
  #pragma unroll
  for (int kc = 0; kc < 8; ++kc) {
    #pragma unroll
    for (int ntl = 0; ntl < 2; ++ntl) {
      const int n = wave * 32 + ntl * 16 + lp;
      f32x4 wlo = {}, whi = {};
      #pragma unroll
      for (int j = 0; j < 8; ++j) {
        const int k = kc * 32 + quad * 8 + j;
        float w = 0.f;
        if (kc < 4) {
          if (k < HH && n < HH) w = Whh[(size_t)layer * HH * HH + n * HH + k];
        } else {
          const int kk = k - 128;
          if (layer > 0 && kk >= 0 && kk < HH && n < HH)
            w = Wih[(size_t)(layer - 1) * HH * HH + n * HH + kk];
        }
        if (j < 4) wlo[j] = w; else whi[j - 4] = w;
      }
      build2(wlo, whi, Bf[kc][ntl][0], Bf[kc][ntl][1]);
    }
  }

  // ---- flags / ring pointers (proven protocol) ----
  int* prog_in  = (layer > 0)      ? wsi + flag_idx(layer - 1, chunk)        : nullptr;
  int* cons_in  = (layer > 0)      ? wsi + 8192 + flag_idx(layer - 1, chunk) : nullptr;
  int* prog_out = (layer < NL - 1) ? wsi + flag_idx(layer, chunk)            : nullptr;
  int* cons_out = (layer < NL - 1) ? wsi + 8192 + flag_idx(layer, chunk)     : nullptr;
  const size_t slot_sz = (size_t)NE;  // 1600 floats
  float* ring_in  = (layer > 0)      ? ring + (size_t)((layer - 1) * NB + chunk) * RDv * slot_sz : nullptr;
  float* ring_out = (layer < NL - 1) ? ring + (size_t)(layer * NB + chunk) * RDv * slot_sz       : nullptr;

  const int jcv[2] = { wave * 32 + lp, wave * 32 + 16 + lp };   // C columns
  const float br[2]  = { bias[jcv[0]], bias[jcv[1]] };
  const float w0r[2] = { wi0s[jcv[0]], wi0s[jcv[1]] };
  const float boutv = bout[0];

  f32x4 hreg[2];             // step-t h values in C layout (deferred stores)
  float dso = 0.f;           // deferred layer-9 output
  float px = 0.f;
  bool have_ring_def = false, have_out_def = false;

  for (int t = 0; t < TTS; ++t) {
    const int par = t & 1, nxt = par ^ 1;
    const bool batch_start = (t & Km) == 0;
    const bool batch_last  = (t & Km) == Km;

    // ---- batch boundary: wait + exposed staging of slot t into parity par ----
    if (batch_start) {
      if (tid == 0) {
        if (layer > 0) {
          while (__hip_atomic_load(prog_in, __ATOMIC_RELAXED, __HIP_MEMORY_SCOPE_AGENT) < t + Kv)
            __builtin_amdgcn_s_sleep(1);
          (void)__hip_atomic_load(prog_in, __ATOMIC_ACQUIRE, __HIP_MEMORY_SCOPE_AGENT);
        }
        if (layer < NL - 1 && t + Kv > RDv) {
          while (__hip_atomic_load(cons_out, __ATOMIC_RELAXED, __HIP_MEMORY_SCOPE_AGENT) < t + Kv - RDv)
            __builtin_amdgcn_s_sleep(1);
        }
      }
      ctl_barrier();
      if (layer > 0) {
        const float* src = ring_in + (size_t)(t & RDm) * slot_sz;
        int i0 = tid * 4;
        f32x4 q0 = {}, q1 = {};
        if (i0 < NE) q0 = *(const f32x4*)(src + i0);
        if (i0 + 1024 < NE) q1 = *(const f32x4*)(src + i0 + 1024);
        if (i0 < NE) *(f32x4*)&ibuf[par][i0 / HH][i0 % HH] = q0;
        if (i0 + 1024 < NE)
          *(f32x4*)&ibuf[par][(i0 + 1024) / HH][(i0 + 1024) % HH] = q1;
      } else if (t == 0) {
        if (tid < BC) xin[0][tid] = x[(size_t)(chunk * BC + tid) * TTS];
      }
      lds_barrier();
    }

    // ---- issue deferred stores from step t-1 (stay in flight past barrier) ----
    if (have_ring_def) {
      float* dst = ring_out + (size_t)((t - 1) & RDm) * slot_sz;
      #pragma unroll
      for (int ntl = 0; ntl < 2; ++ntl)
        if (jcv[ntl] < HH)
          #pragma unroll
          for (int r = 0; r < 4; ++r)
            dst[(size_t)(quad * 4 + r) * HH + jcv[ntl]] = hreg[ntl][r];
      have_ring_def = false;
    }
    if (have_out_def) {
      if ((tid & 15) == 0)
        out[(size_t)(chunk * BC + (tid >> 4)) * TTS + (t - 1)] = dso;
      have_out_def = false;
    }

    // ---- prefetch inp_{t+1} into regs (staged into ibuf[nxt] post-compute) ----
    f32x4 p0 = {}, p1 = {};
    bool pre = false;
    if (layer > 0) {
      if (!batch_last && t + 1 < TTS) {
        const float* src = ring_in + (size_t)((t + 1) & RDm) * slot_sz;
        int i0 = tid * 4;
        if (i0 < NE) p0 = *(const f32x4*)(src + i0);
        if (i0 + 1024 < NE) p1 = *(const f32x4*)(src + i0 + 1024);
        pre = true;
      }
    } else {
      if (t + 1 < TTS && tid < BC) px = x[(size_t)(chunk * BC + tid) * TTS + (t + 1)];
    }

    // ---- MFMA: acc = h @ Whh^T, acc2 = inp @ Wih^T (4 independent chains) ----
    f32x4 acc[2] = {}, acc2[2] = {};
    auto mfma_kc = [&](f32x4* accp, const float (*buf)[HS], int koff, int bfi) {
      short8 A1, A2;
      const float* rp = &buf[lp][koff + quad * 8];
      f32x4 qlo = *(const f32x4*)rp;
      f32x4 qhi = *(const f32x4*)(rp + 4);
      build2(qlo, qhi, A1, A2);
      #pragma unroll
      for (int ntl = 0; ntl < 2; ++ntl) {
        accp[ntl] = __builtin_amdgcn_mfma_f32_16x16x32_bf16(
            A2, Bf[bfi][ntl][0], accp[ntl], 0, 0, 0);   // a2*b1
        accp[ntl] = __builtin_amdgcn_mfma_f32_16x16x32_bf16(
            A1, Bf[bfi][ntl][1], accp[ntl], 0, 0, 0);   // a1*b2
        accp[ntl] = __builtin_amdgcn_mfma_f32_16x16x32_bf16(
            A1, Bf[bfi][ntl][0], accp[ntl], 0, 0, 0);   // a1*b1
      }
    };
    #pragma unroll
    for (int kc = 0; kc < 4; ++kc) mfma_kc(acc, hbuf[par], kc * 32, kc);
    if (layer > 0) {
      #pragma unroll
      for (int kc = 0; kc < 4; ++kc) mfma_kc(acc2, ibuf[par], kc * 32, kc + 4);
    }

    // ---- epilogue: merge chains, bias (+x*w0 layer0), tanh, write hbuf[nxt] ----
    #pragma unroll
    for (int ntl = 0; ntl < 2; ++ntl) {
      #pragma unroll
      for (int r = 0; r < 4; ++r) {
        const int m = quad * 4 + r;
        float v = acc[ntl][r] + acc2[ntl][r] + br[ntl];
        if (layer == 0) v += xin[par][m] * w0r[ntl];
        float h = fast_tanh(v);
        hreg[ntl][r] = h;
        if (jcv[ntl] < HH) hbuf[nxt][m][jcv[ntl]] = h;
      }
    }

    // batch-last ring store cannot be deferred past the flag publish
    if (layer < NL - 1 && batch_last) {
      float* dst = ring_out + (size_t)(t & RDm) * slot_sz;
      #pragma unroll
      for (int ntl = 0; ntl < 2; ++ntl)
        if (jcv[ntl] < HH)
          #pragma unroll
          for (int r = 0; r < 4; ++r)
            dst[(size_t)(quad * 4 + r) * HH + jcv[ntl]] = hreg[ntl][r];
    }

    // ---- stage prefetched inp_{t+1} into ibuf[nxt] / xin[nxt] ----
    if (pre) {
      int i0 = tid * 4;
      if (i0 < NE) *(f32x4*)&ibuf[nxt][i0 / HH][i0 % HH] = p0;
      if (i0 + 1024 < NE)
        *(f32x4*)&ibuf[nxt][(i0 + 1024) / HH][(i0 + 1024) % HH] = p1;
    }
    if (layer == 0 && t + 1 < TTS && tid < BC) xin[nxt][tid] = px;

    lds_barrier();   // LDS ordered; global stores remain in flight

    // ---- flags (once per batch); RELEASE drains all outstanding stores ----
    if (batch_last && tid == 0) {
      if (layer < NL - 1)
        __hip_atomic_store(prog_out, t + 1, __ATOMIC_RELEASE, __HIP_MEMORY_SCOPE_AGENT);
      if (layer > 0)
        __hip_atomic_store(cons_in, t + 1, __ATOMIC_RELAXED, __HIP_MEMORY_SCOPE_AGENT);
    }

    // ---- layer-9 output dot (reads fresh hbuf[nxt]) ----
    if (layer == NL - 1) {
      const int b = tid >> 4, seg = tid & 15;
      float s = 0.f;
      #pragma unroll
      for (int jj = 0; jj < 7; ++jj) {
        const int j = seg * 7 + jj;
        if (j < HH) s += hbuf[nxt][b][j] * wouts[j];
      }
      s += __shfl_xor(s, 1, 16);
      s += __shfl_xor(s, 2, 16);
      s += __shfl_xor(s, 4, 16);
      s += __shfl_xor(s, 8, 16);
      dso = s + boutv;
      if (t < TTS - 1) have_out_def = true;
    }
    if (layer < NL - 1 && !batch_last) have_ring_def = true;
  }

  // flush last layer-9 outputs (t = TTS-1)
  if (layer == NL - 1 && (tid & 15) == 0)
    out[(size_t)(chunk * BC + (tid >> 4)) * TTS + (TTS - 1)] = dso;

  // final hidden state: TTS even -> lives in hbuf[0]
  for (int i = tid; i < NE; i += NT)
    out[(size_t)BBS * TTS + ((size_t)layer * BBS + chunk * BC + i / HH) * HH + i % HH] =
        hbuf[0][i / HH][i % HH];
}

extern "C" void kernel_launch(void* const* d_in, const int* in_sizes, int n_in,
                              void* d_out, int out_size, void* d_ws, size_t ws_size,
                              hipStream_t stream) {
  const float* x    = (const float*)d_in[0];
  const float* h0   = (const float*)d_in[1];
  const float* Wih0 = (const float*)d_in[2];
  const float* Wih  = (const float*)d_in[3];
  const float* Whh  = (const float*)d_in[4];
  const float* bih  = (const float*)d_in[5];
  const float* bhh  = (const float*)d_in[6];
  const float* Wout = (const float*)d_in[7];
  const float* bout = (const float*)d_in[8];
  float* out = (float*)d_out;

  int*   wsi  = (int*)d_ws;
  float* ring = (float*)((char*)d_ws + 65536);

  // Pick deepest ring that fits ws: ring bytes = 9*32 * RD * 6400
  const size_t slot_bytes = (size_t)BC * HH * 4;   // 6400
  int RDv = 32;
  while (RDv > 2 && 65536 + (size_t)(NL - 1) * NB * RDv * slot_bytes > ws_size)
    RDv >>= 1;
  int Kv = RDv / 2;

  hipLaunchKernelGGL(init_ws_kernel, dim3(64), dim3(256), 0, stream, wsi);
  hipLaunchKernelGGL(rnn_pipe, dim3(NL * NB), dim3(NT), 0, stream,
                     x, h0, Wih0, Wih, Whh, bih, bhh, Wout, bout, out, ring, wsi,
                     Kv, RDv);
}